// Round 3
// baseline (1155.294 us; speedup 1.0000x reference)
//
#include <hip/hip_runtime.h>
#include <hip/hip_bf16.h>
#include <cstdint>
#include <cstddef>

#define NN 1000
#define EE 128000
#define LAYERS 6
#define SCALE 0.125f

typedef __attribute__((ext_vector_type(4))) float f32x4;
typedef __attribute__((ext_vector_type(8))) short short8v;

// round-to-nearest-even fp32 -> bf16 (manual, header-version independent)
static __device__ __forceinline__ unsigned short f2bf(float x){
    unsigned int u = __float_as_uint(x);
    unsigned int lsb = (u >> 16) & 1u;
    u += 0x7fffu + lsb;
    return (unsigned short)(u >> 16);
}

// ---------------- sort-by-target (counting sort) ----------------
__global__ void zero_counts(int* cnt){
    cnt[threadIdx.x] = 0;   // buffer is 1024 ints
}

__global__ void hist_kernel(const int* __restrict__ tgt, int* cnt){
    int e = blockIdx.x*256 + threadIdx.x;
    if (e < EE) atomicAdd(&cnt[tgt[e]], 1);
}

__global__ void scan_kernel(const int* __restrict__ cnt, int* offs, int* cursor){
    __shared__ int s[1024];
    int tid = threadIdx.x;
    s[tid] = (tid < NN) ? cnt[tid] : 0;
    __syncthreads();
    for (int st = 1; st < 1024; st <<= 1){
        int v = (tid >= st) ? s[tid-st] : 0;
        __syncthreads();
        s[tid] += v;
        __syncthreads();
    }
    int excl = (tid == 0) ? 0 : s[tid-1];
    if (tid < NN){ offs[tid] = excl; cursor[tid] = excl; }
    if (tid == 0) offs[NN] = s[NN-1];
}

__global__ void scatter_kernel(const int* __restrict__ src, const int* __restrict__ tgt,
                               int* cursor, int* ssrc, int* seid){
    int e = blockIdx.x*256 + threadIdx.x;
    if (e < EE){
        int t = tgt[e];
        int pos = atomicAdd(&cursor[t], 1);
        ssrc[pos] = src[e];
        seid[pos] = e;
    }
}

// ---------------- edge encoder: 4 -> 16 -> 32 ----------------
__global__ __launch_bounds__(256) void edge_enc(
    const float* __restrict__ edge_attr,
    const float* __restrict__ w1, const float* __restrict__ b1,
    const float* __restrict__ w2, const float* __restrict__ b2,
    float* __restrict__ ef)
{
    __shared__ float w1s[64], b1s[16], w2s[512], b2s[32];
    int tid = threadIdx.x;
    if (tid < 64) w1s[tid] = w1[tid];
    if (tid < 16) b1s[tid] = b1[tid];
    if (tid < 32) b2s[tid] = b2[tid];
    w2s[tid] = w2[tid];
    w2s[tid+256] = w2[tid+256];
    __syncthreads();
    int e = blockIdx.x*256 + tid;
    if (e >= EE) return;
    float4 av = *(const float4*)(edge_attr + (size_t)e*4);
    float hd[16];
    #pragma unroll
    for (int i = 0; i < 16; i++){
        float v = av.x*w1s[i] + av.y*w1s[16+i] + av.z*w1s[32+i] + av.w*w1s[48+i] + b1s[i];
        hd[i] = fmaxf(v, 0.f);
    }
    float outv[32];
    #pragma unroll
    for (int k = 0; k < 32; k++){
        float v = b2s[k];
        #pragma unroll
        for (int i = 0; i < 16; i++) v += hd[i]*w2s[i*32+k];
        outv[k] = v;
    }
    float* op = ef + (size_t)e*32;
    #pragma unroll
    for (int k4 = 0; k4 < 8; k4++){
        *(float4*)(op + k4*4) = make_float4(outv[k4*4], outv[k4*4+1], outv[k4*4+2], outv[k4*4+3]);
    }
}

// ---------------- fp32 embed GEMM: h0 = x@W + b + pe, also writes bf16 copy ----------------
__global__ __launch_bounds__(256) void gemm_embed(
    const float* __restrict__ A, const float* __restrict__ W,
    const float* __restrict__ bias, const float* __restrict__ pe,
    float* __restrict__ C, unsigned short* __restrict__ hb,
    int M, int Nn, int Kk)
{
    __shared__ float As[16*68];
    __shared__ float Bs[16*64];
    int tid = threadIdx.x;
    int tx = tid & 15, ty = tid >> 4;
    int row0 = blockIdx.y*64, col0 = blockIdx.x*64;
    float acc[4][4] = {};
    for (int k0 = 0; k0 < Kk; k0 += 16){
        #pragma unroll
        for (int r = 0; r < 4; r++){
            int t = tid + r*256;
            int m = t >> 4, k = t & 15;
            int row = row0 + m;
            As[k*68 + m] = (row < M) ? A[(size_t)row*Kk + k0 + k] : 0.f;
        }
        #pragma unroll
        for (int r = 0; r < 4; r++){
            int t = tid + r*256;
            int k = t >> 6, n = t & 63;
            Bs[k*64 + n] = W[(size_t)(k0+k)*Nn + col0 + n];
        }
        __syncthreads();
        #pragma unroll
        for (int kk = 0; kk < 16; kk++){
            float4 a4 = *(const float4*)&As[kk*68 + ty*4];
            float4 b4 = *(const float4*)&Bs[kk*64 + tx*4];
            float av[4] = {a4.x, a4.y, a4.z, a4.w};
            float bv[4] = {b4.x, b4.y, b4.z, b4.w};
            #pragma unroll
            for (int i = 0; i < 4; i++)
                #pragma unroll
                for (int j = 0; j < 4; j++)
                    acc[i][j] += av[i]*bv[j];
        }
        __syncthreads();
    }
    #pragma unroll
    for (int i = 0; i < 4; i++){
        int row = row0 + ty*4 + i;
        if (row < M){
            #pragma unroll
            for (int j = 0; j < 4; j++){
                int col = col0 + tx*4 + j;
                float v = acc[i][j] + bias[col];
                v += pe[(size_t)row*Nn + col];
                C[(size_t)row*Nn + col] = v;
                hb[(size_t)row*Nn + col] = f2bf(v);
            }
        }
    }
}

// ---------------- per-layer weight transpose + bf16 convert ----------------
// Wt[mat][n][k] = W[mat][layer][k][n] as bf16
__global__ __launch_bounds__(256) void convert_wt(
    const float* __restrict__ Wq, const float* __restrict__ Wk,
    const float* __restrict__ Wv, const float* __restrict__ Ws,
    int layer, unsigned short* __restrict__ Wt)
{
    int bid = blockIdx.x;          // 4 mats * 256 tiles
    int mat = bid >> 8;
    int tile = bid & 255;
    int tk = tile >> 4, tn = tile & 15;
    const float* W = ((mat==0)?Wq:(mat==1)?Wk:(mat==2)?Wv:Ws) + (size_t)layer*512*512;
    unsigned short* dst = Wt + (size_t)mat*512*512;
    __shared__ float tile_s[32][33];
    int tid = threadIdx.x;
    int r = tid >> 3, c0 = (tid & 7)*4;
    float4 v = *(const float4*)(W + (size_t)(tk*32 + r)*512 + tn*32 + c0);
    tile_s[r][c0+0] = v.x; tile_s[r][c0+1] = v.y;
    tile_s[r][c0+2] = v.z; tile_s[r][c0+3] = v.w;
    __syncthreads();
    ushort4 o;
    o.x = f2bf(tile_s[c0+0][r]);
    o.y = f2bf(tile_s[c0+1][r]);
    o.z = f2bf(tile_s[c0+2][r]);
    o.w = f2bf(tile_s[c0+3][r]);
    *(ushort4*)(dst + (size_t)(tn*32 + r)*512 + tk*32 + c0) = o;
}

// ---------------- bf16 MFMA GEMM: {Q,K,V,S} = h @ W^T(mat) + bias ----------------
// block: 256 thr = 4 waves (2x2), tile 64x128, wave tile 32x64, BK=32
__global__ __launch_bounds__(256) void gemm_qkvs_mfma(
    const unsigned short* __restrict__ hb,   // [1024][512] bf16 (rows >=NN garbage, unused)
    const unsigned short* __restrict__ Wt,   // [4][512(n)][512(k)] bf16
    const float* __restrict__ qb, const float* __restrict__ kb,
    const float* __restrict__ vb, const float* __restrict__ sb,
    float* __restrict__ Q, float* __restrict__ K,
    float* __restrict__ V, float* __restrict__ S)
{
    int bid = blockIdx.x;
    int mat = bid >> 6;
    int rem = bid & 63;
    int mt = rem >> 2, nt = rem & 3;
    int row0 = mt*64, col0 = nt*128;
    const unsigned short* W = Wt + (size_t)mat*512*512;
    const float* bias = (mat==0)?qb:(mat==1)?kb:(mat==2)?vb:sb;
    float* C = (mat==0)?Q:(mat==1)?K:(mat==2)?V:S;

    __shared__ __align__(16) unsigned short As[64*40];   // pad 32->40 bf16/row
    __shared__ __align__(16) unsigned short Bs[128*40];

    int tid = threadIdx.x;
    int wid = tid >> 6, l = tid & 63;
    int wm = wid >> 1, wn = wid & 1;

    f32x4 acc[2][4] = {};

    int ar  = tid >> 2, akq = tid & 3;   // A: 64 rows x 4 chunks
    for (int k0 = 0; k0 < 512; k0 += 32){
        *(uint4*)&As[ar*40 + akq*8]        = *(const uint4*)&hb[(size_t)(row0+ar)*512 + k0 + akq*8];
        *(uint4*)&Bs[ar*40 + akq*8]        = *(const uint4*)&W[(size_t)(col0+ar)*512 + k0 + akq*8];
        *(uint4*)&Bs[(ar+64)*40 + akq*8]   = *(const uint4*)&W[(size_t)(col0+ar+64)*512 + k0 + akq*8];
        __syncthreads();
        short8v a0 = *(const short8v*)&As[(wm*32 + (l&15))*40 + (l>>4)*8];
        short8v a1 = *(const short8v*)&As[(wm*32 + 16 + (l&15))*40 + (l>>4)*8];
        #pragma unroll
        for (int nj = 0; nj < 4; nj++){
            short8v b = *(const short8v*)&Bs[(wn*64 + nj*16 + (l&15))*40 + (l>>4)*8];
            acc[0][nj] = __builtin_amdgcn_mfma_f32_16x16x32_bf16(a0, b, acc[0][nj], 0, 0, 0);
            acc[1][nj] = __builtin_amdgcn_mfma_f32_16x16x32_bf16(a1, b, acc[1][nj], 0, 0, 0);
        }
        __syncthreads();
    }
    int rbase = (l >> 4)*4;
    int cl = l & 15;
    #pragma unroll
    for (int mi = 0; mi < 2; mi++){
        #pragma unroll
        for (int nj = 0; nj < 4; nj++){
            #pragma unroll
            for (int r = 0; r < 4; r++){
                int grow = row0 + wm*32 + mi*16 + rbase + r;
                int gcol = col0 + wn*64 + nj*16 + cl;
                if (grow < NN) C[(size_t)grow*512 + gcol] = acc[mi][nj][r] + bias[gcol];
            }
        }
    }
}

// ------------- fused per-node attention (online softmax) + skip + LayerNorm -------------
__global__ __launch_bounds__(256) void attn_layer(
    const float* __restrict__ hcur,
    const float* __restrict__ Qm, const float* __restrict__ Km,
    const float* __restrict__ Vm, const float* __restrict__ SKm,
    const float* __restrict__ ef, const float* __restrict__ e_w_l,
    const float* __restrict__ ln_g_l, const float* __restrict__ ln_b_l,
    const int* __restrict__ ssrc, const int* __restrict__ seid,
    const int* __restrict__ offs,
    float* __restrict__ hnext, unsigned short* __restrict__ hbn)
{
    int tid = threadIdx.x;
    int t = blockIdx.x;

    __shared__ float q_s[8*68];      // per-head stride 68: conflict-free
    __shared__ float qe_s[8*33];
    __shared__ float ef_s[32*33];
    __shared__ float al_s[256];
    __shared__ float red[32];
    __shared__ float red2[32];
    __shared__ float scale_s[8];
    __shared__ float m_s[8];
    __shared__ float d_s[8];
    __shared__ int   src_s[32];

    {
        float v0 = Qm[(size_t)t*512 + tid];
        float v1 = Qm[(size_t)t*512 + 256 + tid];
        q_s[(tid>>6)*68 + (tid&63)] = v0;
        int tid2 = tid + 256;
        q_s[(tid2>>6)*68 + (tid2&63)] = v1;
    }
    if (tid < 8){ m_s[tid] = -1e30f; d_s[tid] = 0.f; }
    __syncthreads();

    // qe[h][d] = sum_c q[h,c] * e_w[d, h*64+c]
    {
        int hh = tid>>5, dd = tid&31;
        const float* wrow = e_w_l + (size_t)dd*512 + hh*64;
        const float* qh = q_s + hh*68;
        float a = 0.f;
        #pragma unroll
        for (int c = 0; c < 64; c++) a += qh[c]*wrow[c];
        qe_s[hh*33 + dd] = a;
    }
    int start = offs[t];
    int deg   = offs[t+1] - start;
    int h  = tid & 7, ie = tid >> 3;
    int h0 = tid >> 6, h1 = 4 + h0, h2 = tid >> 5;
    int wv = tid >> 6, ln = tid & 63;
    int dd2 = tid & 31;
    float acc0 = 0.f, acc1 = 0.f, accE = 0.f;
    __syncthreads();

    for (int cb = 0; cb < deg; cb += 32){
        int nn2 = min(32, deg - cb);
        // stage ef rows (eid loaded redundantly per 32-thread group; L1-cached)
        #pragma unroll
        for (int r = 0; r < 4; r++){
            int idx = tid + r*256;
            int e_i = idx >> 5, d = idx & 31;
            if (e_i < nn2){
                int eid = seid[start + cb + e_i];
                ef_s[e_i*33 + d] = ef[(size_t)eid*32 + d];
            }
        }
        if (tid < nn2) src_s[tid] = ssrc[start + cb + tid];
        __syncthreads();                                 // B1

        float sc = -1e30f;
        if (ie < nn2){
            int s = src_s[ie];
            const float4* kr = (const float4*)(Km + (size_t)s*512 + h*64);
            const float* qh2 = q_s + h*68;
            float a = 0.f;
            #pragma unroll
            for (int c = 0; c < 16; c++){
                float4 kv = kr[c];
                a += qh2[c*4+0]*kv.x + qh2[c*4+1]*kv.y + qh2[c*4+2]*kv.z + qh2[c*4+3]*kv.w;
            }
            const float* efr = ef_s + ie*33;
            const float* qer = qe_s + h*33;
            float b = 0.f;
            #pragma unroll
            for (int d = 0; d < 32; d++) b += efr[d]*qer[d];
            sc = (a + b)*SCALE;
        }
        // per-head chunk max (reduce over ie bits 3..5 of lane)
        float wmax = sc;
        wmax = fmaxf(wmax, __shfl_xor(wmax, 8));
        wmax = fmaxf(wmax, __shfl_xor(wmax, 16));
        wmax = fmaxf(wmax, __shfl_xor(wmax, 32));
        if (ln < 8) red[wv*8 + ln] = wmax;
        __syncthreads();                                 // B2
        if (tid < 8){
            float mo = m_s[tid];
            float cm = fmaxf(fmaxf(red[tid], red[8+tid]), fmaxf(red[16+tid], red[24+tid]));
            float mn = fmaxf(mo, cm);
            scale_s[tid] = __expf(mo - mn);
            m_s[tid] = mn;
        }
        __syncthreads();                                 // B3
        float al = (ie < nn2) ? __expf(sc - m_s[h]) : 0.f;
        al_s[tid] = al;
        float wsum = al;
        wsum += __shfl_xor(wsum, 8);
        wsum += __shfl_xor(wsum, 16);
        wsum += __shfl_xor(wsum, 32);
        if (ln < 8) red2[wv*8 + ln] = wsum;
        float s0 = scale_s[h0], s1 = scale_s[h1], s2 = scale_s[h2];
        acc0 *= s0; acc1 *= s1; accE *= s2;
        __syncthreads();                                 // B4
        if (tid < 8)
            d_s[tid] = d_s[tid]*scale_s[tid] + red2[tid] + red2[8+tid] + red2[16+tid] + red2[24+tid];

        if (nn2 == 32){
            #pragma unroll 8
            for (int i = 0; i < 32; i++){
                int s = src_s[i];
                float a0 = al_s[i*8 + h0];
                float a1 = al_s[i*8 + h1];
                float a2 = al_s[i*8 + h2];
                acc0 += a0 * Vm[(size_t)s*512 + tid];
                acc1 += a1 * Vm[(size_t)s*512 + 256 + tid];
                accE += a2 * ef_s[i*33 + dd2];
            }
        } else {
            for (int i = 0; i < nn2; i++){
                int s = src_s[i];
                float a0 = al_s[i*8 + h0];
                float a1 = al_s[i*8 + h1];
                float a2 = al_s[i*8 + h2];
                acc0 += a0 * Vm[(size_t)s*512 + tid];
                acc1 += a1 * Vm[(size_t)s*512 + 256 + tid];
                accE += a2 * ef_s[i*33 + dd2];
            }
        }
        __syncthreads();                                 // B5
    }

    float dv0 = d_s[h0], dv1 = d_s[h1], dv2 = d_s[h2];
    float inv0 = (dv0 > 0.f) ? 1.f/dv0 : 0.f;
    float inv1 = (dv1 > 0.f) ? 1.f/dv1 : 0.f;
    float inv2 = (dv2 > 0.f) ? 1.f/dv2 : 0.f;
    float r0 = acc0*inv0, r1 = acc1*inv1;
    al_s[tid] = accE*inv2;     // S[h2][d] normalized
    __syncthreads();

    // e-part of message: S[h] @ e_w
    float oe0 = 0.f, oe1 = 0.f;
    {
        const float* a0p = al_s + h0*32;
        const float* a1p = al_s + h1*32;
        #pragma unroll
        for (int d = 0; d < 32; d++){
            oe0 += a0p[d]*e_w_l[(size_t)d*512 + tid];
            oe1 += a1p[d]*e_w_l[(size_t)d*512 + 256 + tid];
        }
    }
    float x0 = r0 + oe0 + SKm[(size_t)t*512 + tid]       + hcur[(size_t)t*512 + tid];
    float x1 = r1 + oe1 + SKm[(size_t)t*512 + 256 + tid] + hcur[(size_t)t*512 + 256 + tid];

    // LayerNorm over 512 (wave shuffles + tiny LDS)
    float sA = x0 + x1, sB = x0*x0 + x1*x1;
    #pragma unroll
    for (int m = 1; m <= 32; m <<= 1){
        sA += __shfl_xor(sA, m);
        sB += __shfl_xor(sB, m);
    }
    if (ln == 0){ red[wv] = sA; red2[wv] = sB; }
    __syncthreads();
    float tot  = red[0] + red[1] + red[2] + red[3];
    float tot2 = red2[0] + red2[1] + red2[2] + red2[3];
    float mu  = tot*(1.f/512.f);
    float var = tot2*(1.f/512.f) - mu*mu;
    float rstd = rsqrtf(var + 1e-5f);
    float y0 = (x0 - mu)*rstd*ln_g_l[tid]     + ln_b_l[tid];
    float y1 = (x1 - mu)*rstd*ln_g_l[256+tid] + ln_b_l[256+tid];
    hnext[(size_t)t*512 + tid]       = y0;
    hnext[(size_t)t*512 + 256 + tid] = y1;
    hbn[(size_t)t*512 + tid]       = f2bf(y0);
    hbn[(size_t)t*512 + 256 + tid] = f2bf(y1);
}

// ---------------- final head: dom + concat + MLP ----------------
__global__ __launch_bounds__(256) void final_head(
    const float* __restrict__ hin,
    const float* __restrict__ dom_w, const float* __restrict__ dom_b,
    const float* __restrict__ w1, const float* __restrict__ b1,
    const float* __restrict__ w2, const float* __restrict__ b2,
    float* __restrict__ out)
{
    int tid = threadIdx.x, t = blockIdx.x;
    __shared__ float h_s[512];
    __shared__ float dom_s[16];
    __shared__ float hid_s[256];
    __shared__ float red[256];
    h_s[tid]     = hin[(size_t)t*512 + tid];
    h_s[tid+256] = hin[(size_t)t*512 + 256 + tid];
    __syncthreads();
    if (tid < 16){
        float a = dom_b[tid];
        for (int i = 0; i < 512; i++) a += h_s[i]*dom_w[i*16 + tid];
        dom_s[tid] = a;
    }
    __syncthreads();
    float acc = b1[tid];
    for (int i = 0; i < 512; i++) acc += h_s[i]*w1[(size_t)i*256 + tid];
    #pragma unroll
    for (int i = 0; i < 16; i++) acc += dom_s[i]*w1[(size_t)(512+i)*256 + tid];
    hid_s[tid] = fmaxf(acc, 0.f);
    __syncthreads();
    int o = tid & 15, g = tid >> 4;
    float p = 0.f;
    #pragma unroll
    for (int j = 0; j < 16; j++) p += hid_s[g*16 + j]*w2[(g*16 + j)*16 + o];
    red[tid] = p;
    __syncthreads();
    if (tid < 16){
        float s2 = b2[tid];
        for (int gg = 0; gg < 16; gg++) s2 += red[gg*16 + tid];
        out[(size_t)t*16 + tid] = s2;
    }
}

// ---------------- launch ----------------
extern "C" void kernel_launch(void* const* d_in, const int* in_sizes, int n_in,
                              void* d_out, int out_size, void* d_ws, size_t ws_size,
                              hipStream_t stream)
{
    const float* x       = (const float*)d_in[0];
    const int*   eidx    = (const int*)  d_in[1];
    const float* eattr   = (const float*)d_in[2];
    const float* embed_w = (const float*)d_in[3];
    const float* embed_b = (const float*)d_in[4];
    const float* pe      = (const float*)d_in[5];
    const float* ee_w1   = (const float*)d_in[6];
    const float* ee_b1   = (const float*)d_in[7];
    const float* ee_w2   = (const float*)d_in[8];
    const float* ee_b2   = (const float*)d_in[9];
    const float* q_w     = (const float*)d_in[10];
    const float* q_b     = (const float*)d_in[11];
    const float* k_w     = (const float*)d_in[12];
    const float* k_b     = (const float*)d_in[13];
    const float* v_w     = (const float*)d_in[14];
    const float* v_b     = (const float*)d_in[15];
    const float* e_w     = (const float*)d_in[16];
    const float* skip_w  = (const float*)d_in[17];
    const float* skip_b  = (const float*)d_in[18];
    const float* ln_g    = (const float*)d_in[19];
    const float* ln_b    = (const float*)d_in[20];
    const float* dom_w   = (const float*)d_in[21];
    const float* dom_b   = (const float*)d_in[22];
    const float* cls_w1  = (const float*)d_in[23];
    const float* cls_b1  = (const float*)d_in[24];
    const float* cls_w2  = (const float*)d_in[25];
    const float* cls_b2  = (const float*)d_in[26];
    float* out = (float*)d_out;

    float* ws = (float*)d_ws;
    size_t o = 0;
    float* h0    = ws + o; o += (size_t)512*NN;
    float* h1    = ws + o; o += (size_t)512*NN;
    float* Qb    = ws + o; o += (size_t)512*NN;
    float* Kb    = ws + o; o += (size_t)512*NN;
    float* Vb    = ws + o; o += (size_t)512*NN;
    float* Sb    = ws + o; o += (size_t)512*NN;
    float* efb   = ws + o; o += (size_t)32*EE;
    unsigned short* hb  = (unsigned short*)(ws + o); o += (size_t)1024*512/2;  // bf16 [1024][512]
    unsigned short* Wtb = (unsigned short*)(ws + o); o += (size_t)4*512*512/2; // bf16 [4][512][512]
    int* cnt    = (int*)(ws + o); o += 1024;
    int* offs   = (int*)(ws + o); o += 1024;
    int* cursor = (int*)(ws + o); o += 1024;
    int* ssrc   = (int*)(ws + o); o += EE;
    int* seid   = (int*)(ws + o); o += EE;

    const int* srcp = eidx;
    const int* tgtp = eidx + EE;

    zero_counts<<<1, 1024, 0, stream>>>(cnt);
    hist_kernel<<<EE/256, 256, 0, stream>>>(tgtp, cnt);
    scan_kernel<<<1, 1024, 0, stream>>>(cnt, offs, cursor);
    scatter_kernel<<<EE/256, 256, 0, stream>>>(srcp, tgtp, cursor, ssrc, seid);
    edge_enc<<<EE/256, 256, 0, stream>>>(eattr, ee_w1, ee_b1, ee_w2, ee_b2, efb);
    gemm_embed<<<dim3(8, 16), 256, 0, stream>>>(x, embed_w, embed_b, pe, h0, hb, NN, 512, 256);

    float* hc = h0;
    float* hn = h1;
    for (int l = 0; l < LAYERS; l++){
        convert_wt<<<1024, 256, 0, stream>>>(q_w, k_w, v_w, skip_w, l, Wtb);
        gemm_qkvs_mfma<<<256, 256, 0, stream>>>(
            hb, Wtb,
            q_b + (size_t)l*512, k_b + (size_t)l*512,
            v_b + (size_t)l*512, skip_b + (size_t)l*512,
            Qb, Kb, Vb, Sb);
        attn_layer<<<NN, 256, 0, stream>>>(
            hc, Qb, Kb, Vb, Sb, efb, e_w + (size_t)l*32*512,
            ln_g + (size_t)l*512, ln_b + (size_t)l*512,
            ssrc, seid, offs, hn, hb);
        float* tmp = hc; hc = hn; hn = tmp;
    }
    final_head<<<NN, 256, 0, stream>>>(hc, dom_w, dom_b, cls_w1, cls_b1, cls_w2, cls_b2, out);
}

// Round 4
// 934.991 us; speedup vs baseline: 1.2356x; 1.2356x over previous
//
#include <hip/hip_runtime.h>
#include <hip/hip_bf16.h>
#include <cstdint>
#include <cstddef>

#define NN 1000
#define EE 128000
#define LAYERS 6
#define SCALE 0.125f
#define MAXDEG 320

typedef __attribute__((ext_vector_type(4))) float f32x4;
typedef __attribute__((ext_vector_type(8))) short short8v;

static __device__ __forceinline__ unsigned short f2bf(float x){
    unsigned int u = __float_as_uint(x);
    unsigned int lsb = (u >> 16) & 1u;
    u += 0x7fffu + lsb;
    return (unsigned short)(u >> 16);
}

// ---------------- sort-by-target (counting sort) ----------------
__global__ void zero_counts(int* cnt){
    cnt[threadIdx.x] = 0;
}

__global__ void hist_kernel(const int* __restrict__ tgt, int* cnt){
    int e = blockIdx.x*256 + threadIdx.x;
    if (e < EE) atomicAdd(&cnt[tgt[e]], 1);
}

__global__ void scan_kernel(const int* __restrict__ cnt, int* offs, int* cursor){
    __shared__ int s[1024];
    int tid = threadIdx.x;
    s[tid] = (tid < NN) ? cnt[tid] : 0;
    __syncthreads();
    for (int st = 1; st < 1024; st <<= 1){
        int v = (tid >= st) ? s[tid-st] : 0;
        __syncthreads();
        s[tid] += v;
        __syncthreads();
    }
    int excl = (tid == 0) ? 0 : s[tid-1];
    if (tid < NN){ offs[tid] = excl; cursor[tid] = excl; }
    if (tid == 0) offs[NN] = s[NN-1];
}

// also records epos[e] = sorted position (inverse permutation)
__global__ void scatter_kernel(const int* __restrict__ src, const int* __restrict__ tgt,
                               int* cursor, int* ssrc, int* epos){
    int e = blockIdx.x*256 + threadIdx.x;
    if (e < EE){
        int t = tgt[e];
        int pos = atomicAdd(&cursor[t], 1);
        ssrc[pos] = src[e];
        epos[e] = pos;
    }
}

// ---------------- edge encoder: 4 -> 16 -> 32, scatter-write to sorted order ----------------
__global__ __launch_bounds__(256) void edge_enc(
    const float* __restrict__ edge_attr,
    const float* __restrict__ w1, const float* __restrict__ b1,
    const float* __restrict__ w2, const float* __restrict__ b2,
    const int* __restrict__ epos,
    float* __restrict__ efs)
{
    __shared__ float w1s[64], b1s[16], w2s[512], b2s[32];
    int tid = threadIdx.x;
    if (tid < 64) w1s[tid] = w1[tid];
    if (tid < 16) b1s[tid] = b1[tid];
    if (tid < 32) b2s[tid] = b2[tid];
    w2s[tid] = w2[tid];
    w2s[tid+256] = w2[tid+256];
    __syncthreads();
    int e = blockIdx.x*256 + tid;
    if (e >= EE) return;
    float4 av = *(const float4*)(edge_attr + (size_t)e*4);
    float hd[16];
    #pragma unroll
    for (int i = 0; i < 16; i++){
        float v = av.x*w1s[i] + av.y*w1s[16+i] + av.z*w1s[32+i] + av.w*w1s[48+i] + b1s[i];
        hd[i] = fmaxf(v, 0.f);
    }
    float outv[32];
    #pragma unroll
    for (int k = 0; k < 32; k++){
        float v = b2s[k];
        #pragma unroll
        for (int i = 0; i < 16; i++) v += hd[i]*w2s[i*32+k];
        outv[k] = v;
    }
    float* op = efs + (size_t)epos[e]*32;
    #pragma unroll
    for (int k4 = 0; k4 < 8; k4++){
        *(float4*)(op + k4*4) = make_float4(outv[k4*4], outv[k4*4+1], outv[k4*4+2], outv[k4*4+3]);
    }
}

// ---------------- x -> bf16 (zero-pad rows >= NN) ----------------
__global__ __launch_bounds__(256) void convert_x(const float* __restrict__ x, unsigned short* __restrict__ xb){
    int row = blockIdx.x;          // 0..1023
    int c = threadIdx.x;           // 0..255
    xb[(size_t)row*256 + c] = (row < NN) ? f2bf(x[(size_t)row*256 + c]) : (unsigned short)0;
}

// ---------------- generic transpose-convert: dst[n][k] = bf16(src[k][n]) ----------------
// grid: (Nn/32, Kk/32)
__global__ __launch_bounds__(256) void tconv(const float* __restrict__ src, unsigned short* __restrict__ dst,
                                             int Kk, int Nn){
    int tn = blockIdx.x, tk = blockIdx.y;
    __shared__ float ts[32][33];
    int tid = threadIdx.x;
    int r = tid >> 3, c0 = (tid & 7)*4;
    float4 v = *(const float4*)(src + (size_t)(tk*32 + r)*Nn + tn*32 + c0);
    ts[r][c0+0] = v.x; ts[r][c0+1] = v.y; ts[r][c0+2] = v.z; ts[r][c0+3] = v.w;
    __syncthreads();
    ushort4 o;
    o.x = f2bf(ts[c0+0][r]); o.y = f2bf(ts[c0+1][r]);
    o.z = f2bf(ts[c0+2][r]); o.w = f2bf(ts[c0+3][r]);
    *(ushort4*)(dst + (size_t)(tn*32 + r)*Kk + tk*32 + c0) = o;
}

// all 24 qkvs matrices at once: mm = l*4+m, 256 tiles per matrix
__global__ __launch_bounds__(256) void tconv24(
    const float* __restrict__ Wq, const float* __restrict__ Wk,
    const float* __restrict__ Wv, const float* __restrict__ Ws,
    unsigned short* __restrict__ Wt)
{
    int bid = blockIdx.x;
    int mm = bid >> 8;             // 0..23
    int tile = bid & 255;
    int tk = tile >> 4, tn = tile & 15;
    int l = mm >> 2, m = mm & 3;
    const float* W = ((m==0)?Wq:(m==1)?Wk:(m==2)?Wv:Ws) + (size_t)l*512*512;
    unsigned short* dst = Wt + (size_t)mm*512*512;
    __shared__ float ts[32][33];
    int tid = threadIdx.x;
    int r = tid >> 3, c0 = (tid & 7)*4;
    float4 v = *(const float4*)(W + (size_t)(tk*32 + r)*512 + tn*32 + c0);
    ts[r][c0+0] = v.x; ts[r][c0+1] = v.y; ts[r][c0+2] = v.z; ts[r][c0+3] = v.w;
    __syncthreads();
    ushort4 o;
    o.x = f2bf(ts[c0+0][r]); o.y = f2bf(ts[c0+1][r]);
    o.z = f2bf(ts[c0+2][r]); o.w = f2bf(ts[c0+3][r]);
    *(ushort4*)(dst + (size_t)(tn*32 + r)*512 + tk*32 + c0) = o;
}

// ---------------- MFMA embed GEMM: h0 = x@W + b + pe (K=256), writes fp32 + bf16 ----------------
__global__ __launch_bounds__(256) void gemm_embed_mfma(
    const unsigned short* __restrict__ xb,   // [1024][256] bf16
    const unsigned short* __restrict__ ewt,  // [512(n)][256(k)] bf16
    const float* __restrict__ bias, const float* __restrict__ pe,
    float* __restrict__ C, unsigned short* __restrict__ hb)
{
    int bid = blockIdx.x;                    // 16 row-tiles x 4 col-tiles
    int mt = bid >> 2, nt = bid & 3;
    int row0 = mt*64, col0 = nt*128;

    __shared__ __align__(16) unsigned short As[64*40];
    __shared__ __align__(16) unsigned short Bs[128*40];

    int tid = threadIdx.x;
    int wid = tid >> 6, l = tid & 63;
    int wm = wid >> 1, wn = wid & 1;

    f32x4 acc[2][4] = {};
    int ar = tid >> 2, akq = tid & 3;
    for (int k0 = 0; k0 < 256; k0 += 32){
        *(uint4*)&As[ar*40 + akq*8]      = *(const uint4*)&xb[(size_t)(row0+ar)*256 + k0 + akq*8];
        *(uint4*)&Bs[ar*40 + akq*8]      = *(const uint4*)&ewt[(size_t)(col0+ar)*256 + k0 + akq*8];
        *(uint4*)&Bs[(ar+64)*40 + akq*8] = *(const uint4*)&ewt[(size_t)(col0+ar+64)*256 + k0 + akq*8];
        __syncthreads();
        short8v a0 = *(const short8v*)&As[(wm*32 + (l&15))*40 + (l>>4)*8];
        short8v a1 = *(const short8v*)&As[(wm*32 + 16 + (l&15))*40 + (l>>4)*8];
        #pragma unroll
        for (int nj = 0; nj < 4; nj++){
            short8v b = *(const short8v*)&Bs[(wn*64 + nj*16 + (l&15))*40 + (l>>4)*8];
            acc[0][nj] = __builtin_amdgcn_mfma_f32_16x16x32_bf16(a0, b, acc[0][nj], 0, 0, 0);
            acc[1][nj] = __builtin_amdgcn_mfma_f32_16x16x32_bf16(a1, b, acc[1][nj], 0, 0, 0);
        }
        __syncthreads();
    }
    int rbase = (l >> 4)*4, cl = l & 15;
    #pragma unroll
    for (int mi = 0; mi < 2; mi++)
        #pragma unroll
        for (int nj = 0; nj < 4; nj++)
            #pragma unroll
            for (int r = 0; r < 4; r++){
                int grow = row0 + wm*32 + mi*16 + rbase + r;
                int gcol = col0 + wn*64 + nj*16 + cl;
                if (grow < NN){
                    float v = acc[mi][nj][r] + bias[gcol] + pe[(size_t)grow*512 + gcol];
                    C[(size_t)grow*512 + gcol] = v;
                    hb[(size_t)grow*512 + gcol] = f2bf(v);
                }
            }
}

// ---------------- bf16 MFMA GEMM: {Q,K,V,S} = h @ W^T + bias ----------------
__global__ __launch_bounds__(256) void gemm_qkvs_mfma(
    const unsigned short* __restrict__ hb,   // [1024][512] bf16
    const unsigned short* __restrict__ Wt,   // [4][512(n)][512(k)] bf16 (this layer)
    const float* __restrict__ qb, const float* __restrict__ kb,
    const float* __restrict__ vb, const float* __restrict__ sb,
    float* __restrict__ Q, float* __restrict__ K,
    float* __restrict__ V, float* __restrict__ S)
{
    int bid = blockIdx.x;
    int mat = bid >> 6;
    int rem = bid & 63;
    int mt = rem >> 2, nt = rem & 3;
    int row0 = mt*64, col0 = nt*128;
    const unsigned short* W = Wt + (size_t)mat*512*512;
    const float* bias = (mat==0)?qb:(mat==1)?kb:(mat==2)?vb:sb;
    float* C = (mat==0)?Q:(mat==1)?K:(mat==2)?V:S;

    __shared__ __align__(16) unsigned short As[64*40];
    __shared__ __align__(16) unsigned short Bs[128*40];

    int tid = threadIdx.x;
    int wid = tid >> 6, l = tid & 63;
    int wm = wid >> 1, wn = wid & 1;

    f32x4 acc[2][4] = {};
    int ar = tid >> 2, akq = tid & 3;
    for (int k0 = 0; k0 < 512; k0 += 32){
        *(uint4*)&As[ar*40 + akq*8]      = *(const uint4*)&hb[(size_t)(row0+ar)*512 + k0 + akq*8];
        *(uint4*)&Bs[ar*40 + akq*8]      = *(const uint4*)&W[(size_t)(col0+ar)*512 + k0 + akq*8];
        *(uint4*)&Bs[(ar+64)*40 + akq*8] = *(const uint4*)&W[(size_t)(col0+ar+64)*512 + k0 + akq*8];
        __syncthreads();
        short8v a0 = *(const short8v*)&As[(wm*32 + (l&15))*40 + (l>>4)*8];
        short8v a1 = *(const short8v*)&As[(wm*32 + 16 + (l&15))*40 + (l>>4)*8];
        #pragma unroll
        for (int nj = 0; nj < 4; nj++){
            short8v b = *(const short8v*)&Bs[(wn*64 + nj*16 + (l&15))*40 + (l>>4)*8];
            acc[0][nj] = __builtin_amdgcn_mfma_f32_16x16x32_bf16(a0, b, acc[0][nj], 0, 0, 0);
            acc[1][nj] = __builtin_amdgcn_mfma_f32_16x16x32_bf16(a1, b, acc[1][nj], 0, 0, 0);
        }
        __syncthreads();
    }
    int rbase = (l >> 4)*4, cl = l & 15;
    #pragma unroll
    for (int mi = 0; mi < 2; mi++)
        #pragma unroll
        for (int nj = 0; nj < 4; nj++)
            #pragma unroll
            for (int r = 0; r < 4; r++){
                int grow = row0 + wm*32 + mi*16 + rbase + r;
                int gcol = col0 + wn*64 + nj*16 + cl;
                if (grow < NN) C[(size_t)grow*512 + gcol] = acc[mi][nj][r] + bias[gcol];
            }
}

// ------------- fused per-node attention (two-pass, LDS scores) + skip + LayerNorm -------------
// 512 threads per block, one block per target node. No barriers inside edge loops.
__global__ __launch_bounds__(512) void attn_layer(
    const float* __restrict__ hcur,
    const float* __restrict__ Qm, const float* __restrict__ Km,
    const float* __restrict__ Vm, const float* __restrict__ SKm,
    const float* __restrict__ efs, const float* __restrict__ e_w_l,
    const float* __restrict__ ln_g_l, const float* __restrict__ ln_b_l,
    const int* __restrict__ ssrc, const int* __restrict__ offs,
    float* __restrict__ hnext, unsigned short* __restrict__ hbn)
{
    int tid = threadIdx.x;
    int t = blockIdx.x;

    __shared__ float q_s[8*68];
    __shared__ float qe_s[8*36];
    __shared__ float sc_s[MAXDEG*8];
    __shared__ float red[64], red2[64];
    __shared__ float m_s[8], d_s[8];
    __shared__ float2 pv_s[2][256];
    __shared__ float pe_s[2][256];
    __shared__ float s_s[256];

    {
        int c = tid;
        float qv = Qm[(size_t)t*512 + c];
        q_s[(c>>6)*68 + (c&63)] = qv;
    }
    __syncthreads();
    if (tid < 256){
        int hh = tid>>5, dd = tid&31;
        const float* wrow = e_w_l + (size_t)dd*512 + hh*64;
        const float* qh = q_s + hh*68;
        float a = 0.f;
        #pragma unroll
        for (int c = 0; c < 64; c++) a += qh[c]*wrow[c];
        qe_s[hh*36 + dd] = a;
    }
    int start = offs[t], deg = offs[t+1] - start;
    int h = tid & 7, ie = tid >> 3;      // 64 edges x 8 heads in flight
    int wv = tid >> 6, ln = tid & 63;
    __syncthreads();

    // ---- pass 1: scores (no barriers) ----
    float lmax = -1e30f;
    const float* qh2 = q_s + h*68;
    const float* qe2 = qe_s + h*36;
    for (int i = ie; i < deg; i += 64){
        int s = ssrc[start+i];
        const float4* kr = (const float4*)(Km + (size_t)s*512 + h*64);
        float a = 0.f;
        #pragma unroll
        for (int c4 = 0; c4 < 16; c4++){
            float4 kv = kr[c4];
            a += qh2[c4*4+0]*kv.x + qh2[c4*4+1]*kv.y + qh2[c4*4+2]*kv.z + qh2[c4*4+3]*kv.w;
        }
        const float4* er = (const float4*)(efs + (size_t)(start+i)*32);
        float b = 0.f;
        #pragma unroll
        for (int d4 = 0; d4 < 8; d4++){
            float4 ev = er[d4];
            b += qe2[d4*4+0]*ev.x + qe2[d4*4+1]*ev.y + qe2[d4*4+2]*ev.z + qe2[d4*4+3]*ev.w;
        }
        float sc = (a + b)*SCALE;
        sc_s[i*8 + h] = sc;
        lmax = fmaxf(lmax, sc);
    }
    lmax = fmaxf(lmax, __shfl_xor(lmax, 8));
    lmax = fmaxf(lmax, __shfl_xor(lmax, 16));
    lmax = fmaxf(lmax, __shfl_xor(lmax, 32));
    if (ln < 8) red[wv*8 + ln] = lmax;
    __syncthreads();
    if (tid < 8){
        float m = red[tid];
        #pragma unroll
        for (int w = 1; w < 8; w++) m = fmaxf(m, red[w*8 + tid]);
        m_s[tid] = m;
    }
    __syncthreads();

    // ---- exp sweep + denominator ----
    float den = 0.f;
    {
        float mh = m_s[h];
        for (int i = ie; i < deg; i += 64){
            float al = __expf(sc_s[i*8 + h] - mh);
            sc_s[i*8 + h] = al;
            den += al;
        }
    }
    den += __shfl_xor(den, 8);
    den += __shfl_xor(den, 16);
    den += __shfl_xor(den, 32);
    if (ln < 8) red2[wv*8 + ln] = den;
    __syncthreads();
    if (tid < 8){
        float d = 0.f;
        #pragma unroll
        for (int w = 0; w < 8; w++) d += red2[w*8 + tid];
        d_s[tid] = d;
    }
    __syncthreads();

    // ---- pass 2: weighted accumulation (no barriers in loop) ----
    int c2 = tid & 255, g = tid >> 8;
    int h2 = c2 >> 5, dd = c2 & 31;
    float2 acc = make_float2(0.f, 0.f);
    float accE = 0.f;
    const float2* Vm2 = (const float2*)Vm;
    #pragma unroll 4
    for (int i = g; i < deg; i += 2){
        int s = ssrc[start+i];
        float al = sc_s[i*8 + h2];
        float2 v = Vm2[(size_t)s*256 + c2];
        acc.x += al*v.x;
        acc.y += al*v.y;
        accE += al * efs[(size_t)(start+i)*32 + dd];
    }
    pv_s[g][c2] = acc;
    pe_s[g][c2] = accE;
    __syncthreads();
    if (tid < 256){
        float dv = d_s[tid>>5];
        float invd = (dv > 0.f) ? 1.f/dv : 0.f;
        s_s[tid] = (pe_s[0][tid] + pe_s[1][tid]) * invd;
    }
    __syncthreads();

    int c = tid;
    int hh = c >> 6;
    float dv = d_s[hh];
    float invd = (dv > 0.f) ? 1.f/dv : 0.f;
    float2 v0 = pv_s[0][c>>1], v1 = pv_s[1][c>>1];
    float vtot = (c & 1) ? (v0.y + v1.y) : (v0.x + v1.x);
    float r = vtot * invd;
    float oe = 0.f;
    const float* sp = s_s + hh*32;
    #pragma unroll
    for (int d = 0; d < 32; d++) oe += sp[d]*e_w_l[(size_t)d*512 + c];
    float x = r + oe + SKm[(size_t)t*512 + c] + hcur[(size_t)t*512 + c];

    // LayerNorm over 512 (one value per thread)
    float sA = x, sB = x*x;
    #pragma unroll
    for (int m2 = 1; m2 <= 32; m2 <<= 1){
        sA += __shfl_xor(sA, m2);
        sB += __shfl_xor(sB, m2);
    }
    if (ln == 0){ red[wv] = sA; red2[wv] = sB; }
    __syncthreads();
    float tot = 0.f, tot2 = 0.f;
    #pragma unroll
    for (int w = 0; w < 8; w++){ tot += red[w]; tot2 += red2[w]; }
    float mu  = tot*(1.f/512.f);
    float var = tot2*(1.f/512.f) - mu*mu;
    float rstd = rsqrtf(var + 1e-5f);
    float y = (x - mu)*rstd*ln_g_l[c] + ln_b_l[c];
    hnext[(size_t)t*512 + c] = y;
    hbn[(size_t)t*512 + c]   = f2bf(y);
}

// ---------------- final head: dom + concat + MLP ----------------
__global__ __launch_bounds__(256) void final_head(
    const float* __restrict__ hin,
    const float* __restrict__ dom_w, const float* __restrict__ dom_b,
    const float* __restrict__ w1, const float* __restrict__ b1,
    const float* __restrict__ w2, const float* __restrict__ b2,
    float* __restrict__ out)
{
    int tid = threadIdx.x, t = blockIdx.x;
    __shared__ float h_s[512];
    __shared__ float dom_s[16];
    __shared__ float hid_s[256];
    __shared__ float red[256];
    h_s[tid]     = hin[(size_t)t*512 + tid];
    h_s[tid+256] = hin[(size_t)t*512 + 256 + tid];
    __syncthreads();
    if (tid < 16){
        float a = dom_b[tid];
        for (int i = 0; i < 512; i++) a += h_s[i]*dom_w[i*16 + tid];
        dom_s[tid] = a;
    }
    __syncthreads();
    float acc = b1[tid];
    for (int i = 0; i < 512; i++) acc += h_s[i]*w1[(size_t)i*256 + tid];
    #pragma unroll
    for (int i = 0; i < 16; i++) acc += dom_s[i]*w1[(size_t)(512+i)*256 + tid];
    hid_s[tid] = fmaxf(acc, 0.f);
    __syncthreads();
    int o = tid & 15, g = tid >> 4;
    float p = 0.f;
    #pragma unroll
    for (int j = 0; j < 16; j++) p += hid_s[g*16 + j]*w2[(g*16 + j)*16 + o];
    red[tid] = p;
    __syncthreads();
    if (tid < 16){
        float s2 = b2[tid];
        for (int gg = 0; gg < 16; gg++) s2 += red[gg*16 + tid];
        out[(size_t)t*16 + tid] = s2;
    }
}

// ---------------- launch ----------------
extern "C" void kernel_launch(void* const* d_in, const int* in_sizes, int n_in,
                              void* d_out, int out_size, void* d_ws, size_t ws_size,
                              hipStream_t stream)
{
    const float* x       = (const float*)d_in[0];
    const int*   eidx    = (const int*)  d_in[1];
    const float* eattr   = (const float*)d_in[2];
    const float* embed_w = (const float*)d_in[3];
    const float* embed_b = (const float*)d_in[4];
    const float* pe      = (const float*)d_in[5];
    const float* ee_w1   = (const float*)d_in[6];
    const float* ee_b1   = (const float*)d_in[7];
    const float* ee_w2   = (const float*)d_in[8];
    const float* ee_b2   = (const float*)d_in[9];
    const float* q_w     = (const float*)d_in[10];
    const float* q_b     = (const float*)d_in[11];
    const float* k_w     = (const float*)d_in[12];
    const float* k_b     = (const float*)d_in[13];
    const float* v_w     = (const float*)d_in[14];
    const float* v_b     = (const float*)d_in[15];
    const float* e_w     = (const float*)d_in[16];
    const float* skip_w  = (const float*)d_in[17];
    const float* skip_b  = (const float*)d_in[18];
    const float* ln_g    = (const float*)d_in[19];
    const float* ln_b    = (const float*)d_in[20];
    const float* dom_w   = (const float*)d_in[21];
    const float* dom_b   = (const float*)d_in[22];
    const float* cls_w1  = (const float*)d_in[23];
    const float* cls_b1  = (const float*)d_in[24];
    const float* cls_w2  = (const float*)d_in[25];
    const float* cls_b2  = (const float*)d_in[26];
    float* out = (float*)d_out;

    float* ws = (float*)d_ws;
    size_t o = 0;
    float* h0    = ws + o; o += (size_t)512*NN;
    float* h1    = ws + o; o += (size_t)512*NN;
    float* Qb    = ws + o; o += (size_t)512*NN;
    float* Kb    = ws + o; o += (size_t)512*NN;
    float* Vb    = ws + o; o += (size_t)512*NN;
    float* Sb    = ws + o; o += (size_t)512*NN;
    float* efs   = ws + o; o += (size_t)32*EE;
    unsigned short* hb  = (unsigned short*)(ws + o); o += (size_t)1024*512/2;     // bf16 [1024][512]
    unsigned short* xb  = (unsigned short*)(ws + o); o += (size_t)1024*256/2;     // bf16 [1024][256]
    unsigned short* ewt = (unsigned short*)(ws + o); o += (size_t)512*256/2;      // bf16 [512][256]
    unsigned short* Wtb = (unsigned short*)(ws + o); o += (size_t)24*512*512/2;   // bf16 [24][512][512]
    int* cnt    = (int*)(ws + o); o += 1024;
    int* offs   = (int*)(ws + o); o += 1024;
    int* cursor = (int*)(ws + o); o += 1024;
    int* ssrc   = (int*)(ws + o); o += EE;
    int* epos   = (int*)(ws + o); o += EE;

    const int* srcp = eidx;
    const int* tgtp = eidx + EE;

    zero_counts<<<1, 1024, 0, stream>>>(cnt);
    hist_kernel<<<EE/256, 256, 0, stream>>>(tgtp, cnt);
    scan_kernel<<<1, 1024, 0, stream>>>(cnt, offs, cursor);
    scatter_kernel<<<EE/256, 256, 0, stream>>>(srcp, tgtp, cursor, ssrc, epos);
    edge_enc<<<EE/256, 256, 0, stream>>>(eattr, ee_w1, ee_b1, ee_w2, ee_b2, epos, efs);
    convert_x<<<1024, 256, 0, stream>>>(x, xb);
    tconv<<<dim3(512/32, 256/32), 256, 0, stream>>>(embed_w, ewt, 256, 512);
    tconv24<<<24*256, 256, 0, stream>>>(q_w, k_w, v_w, skip_w, Wtb);
    gemm_embed_mfma<<<64, 256, 0, stream>>>(xb, ewt, embed_b, pe, h0, hb);

    float* hc = h0;
    float* hn = h1;
    for (int l = 0; l < LAYERS; l++){
        gemm_qkvs_mfma<<<256, 256, 0, stream>>>(
            hb, Wtb + (size_t)l*4*512*512,
            q_b + (size_t)l*512, k_b + (size_t)l*512,
            v_b + (size_t)l*512, skip_b + (size_t)l*512,
            Qb, Kb, Vb, Sb);
        attn_layer<<<NN, 512, 0, stream>>>(
            hc, Qb, Kb, Vb, Sb, efs, e_w + (size_t)l*32*512,
            ln_g + (size_t)l*512, ln_b + (size_t)l*512,
            ssrc, offs, hn, hb);
        float* tmp = hc; hc = hn; hn = tmp;
    }
    final_head<<<NN, 256, 0, stream>>>(hc, dom_w, dom_b, cls_w1, cls_b1, cls_w2, cls_b2, out);
}

// Round 5
// 684.157 us; speedup vs baseline: 1.6886x; 1.3666x over previous
//
#include <hip/hip_runtime.h>
#include <hip/hip_bf16.h>
#include <cstdint>
#include <cstddef>

#define NN 1000
#define EE 128000
#define LAYERS 6
#define SCALE 0.125f
#define MAXDEG 320

typedef __attribute__((ext_vector_type(4))) float f32x4;
typedef __attribute__((ext_vector_type(8))) short short8v;

static __device__ __forceinline__ unsigned short f2bf(float x){
    unsigned int u = __float_as_uint(x);
    unsigned int lsb = (u >> 16) & 1u;
    u += 0x7fffu + lsb;
    return (unsigned short)(u >> 16);
}

// ---------------- sort-by-target (counting sort) ----------------
__global__ void zero_counts(int* cnt){
    cnt[threadIdx.x] = 0;
}

__global__ void hist_kernel(const int* __restrict__ tgt, int* cnt){
    int e = blockIdx.x*256 + threadIdx.x;
    if (e < EE) atomicAdd(&cnt[tgt[e]], 1);
}

__global__ void scan_kernel(const int* __restrict__ cnt, int* offs, int* cursor){
    __shared__ int s[1024];
    int tid = threadIdx.x;
    s[tid] = (tid < NN) ? cnt[tid] : 0;
    __syncthreads();
    for (int st = 1; st < 1024; st <<= 1){
        int v = (tid >= st) ? s[tid-st] : 0;
        __syncthreads();
        s[tid] += v;
        __syncthreads();
    }
    int excl = (tid == 0) ? 0 : s[tid-1];
    if (tid < NN){ offs[tid] = excl; cursor[tid] = excl; }
    if (tid == 0) offs[NN] = s[NN-1];
}

__global__ void scatter_kernel(const int* __restrict__ src, const int* __restrict__ tgt,
                               int* cursor, int* ssrc, int* epos){
    int e = blockIdx.x*256 + threadIdx.x;
    if (e < EE){
        int t = tgt[e];
        int pos = atomicAdd(&cursor[t], 1);
        ssrc[pos] = src[e];
        epos[e] = pos;
    }
}

// ---------------- edge encoder: 4 -> 16 -> 32, scatter-write to sorted order ----------------
__global__ __launch_bounds__(256) void edge_enc(
    const float* __restrict__ edge_attr,
    const float* __restrict__ w1, const float* __restrict__ b1,
    const float* __restrict__ w2, const float* __restrict__ b2,
    const int* __restrict__ epos,
    float* __restrict__ efs)
{
    __shared__ float w1s[64], b1s[16], w2s[512], b2s[32];
    int tid = threadIdx.x;
    if (tid < 64) w1s[tid] = w1[tid];
    if (tid < 16) b1s[tid] = b1[tid];
    if (tid < 32) b2s[tid] = b2[tid];
    w2s[tid] = w2[tid];
    w2s[tid+256] = w2[tid+256];
    __syncthreads();
    int e = blockIdx.x*256 + tid;
    if (e >= EE) return;
    float4 av = *(const float4*)(edge_attr + (size_t)e*4);
    float hd[16];
    #pragma unroll
    for (int i = 0; i < 16; i++){
        float v = av.x*w1s[i] + av.y*w1s[16+i] + av.z*w1s[32+i] + av.w*w1s[48+i] + b1s[i];
        hd[i] = fmaxf(v, 0.f);
    }
    float outv[32];
    #pragma unroll
    for (int k = 0; k < 32; k++){
        float v = b2s[k];
        #pragma unroll
        for (int i = 0; i < 16; i++) v += hd[i]*w2s[i*32+k];
        outv[k] = v;
    }
    float* op = efs + (size_t)epos[e]*32;
    #pragma unroll
    for (int k4 = 0; k4 < 8; k4++){
        *(float4*)(op + k4*4) = make_float4(outv[k4*4], outv[k4*4+1], outv[k4*4+2], outv[k4*4+3]);
    }
}

// ---------------- x -> bf16 (zero-pad rows >= NN) ----------------
__global__ __launch_bounds__(256) void convert_x(const float* __restrict__ x, unsigned short* __restrict__ xb){
    int row = blockIdx.x;
    int c = threadIdx.x;
    xb[(size_t)row*256 + c] = (row < NN) ? f2bf(x[(size_t)row*256 + c]) : (unsigned short)0;
}

// ---------------- transpose-convert: dst[n][k] = bf16(src[k][n]) ----------------
__global__ __launch_bounds__(256) void tconv(const float* __restrict__ src, unsigned short* __restrict__ dst,
                                             int Kk, int Nn){
    int tn = blockIdx.x, tk = blockIdx.y;
    __shared__ float ts[32][33];
    int tid = threadIdx.x;
    int r = tid >> 3, c0 = (tid & 7)*4;
    float4 v = *(const float4*)(src + (size_t)(tk*32 + r)*Nn + tn*32 + c0);
    ts[r][c0+0] = v.x; ts[r][c0+1] = v.y; ts[r][c0+2] = v.z; ts[r][c0+3] = v.w;
    __syncthreads();
    ushort4 o;
    o.x = f2bf(ts[c0+0][r]); o.y = f2bf(ts[c0+1][r]);
    o.z = f2bf(ts[c0+2][r]); o.w = f2bf(ts[c0+3][r]);
    *(ushort4*)(dst + (size_t)(tn*32 + r)*Kk + tk*32 + c0) = o;
}

__global__ __launch_bounds__(256) void tconv24(
    const float* __restrict__ Wq, const float* __restrict__ Wk,
    const float* __restrict__ Wv, const float* __restrict__ Ws,
    unsigned short* __restrict__ Wt)
{
    int bid = blockIdx.x;
    int mm = bid >> 8;
    int tile = bid & 255;
    int tk = tile >> 4, tn = tile & 15;
    int l = mm >> 2, m = mm & 3;
    const float* W = ((m==0)?Wq:(m==1)?Wk:(m==2)?Wv:Ws) + (size_t)l*512*512;
    unsigned short* dst = Wt + (size_t)mm*512*512;
    __shared__ float ts[32][33];
    int tid = threadIdx.x;
    int r = tid >> 3, c0 = (tid & 7)*4;
    float4 v = *(const float4*)(W + (size_t)(tk*32 + r)*512 + tn*32 + c0);
    ts[r][c0+0] = v.x; ts[r][c0+1] = v.y; ts[r][c0+2] = v.z; ts[r][c0+3] = v.w;
    __syncthreads();
    ushort4 o;
    o.x = f2bf(ts[c0+0][r]); o.y = f2bf(ts[c0+1][r]);
    o.z = f2bf(ts[c0+2][r]); o.w = f2bf(ts[c0+3][r]);
    *(ushort4*)(dst + (size_t)(tn*32 + r)*512 + tk*32 + c0) = o;
}

// ---------------- MFMA embed GEMM: h0 = x@W + b + pe (K=256), fp32 + bf16 out ----------------
__global__ __launch_bounds__(256) void gemm_embed_mfma(
    const unsigned short* __restrict__ xb,
    const unsigned short* __restrict__ ewt,
    const float* __restrict__ bias, const float* __restrict__ pe,
    float* __restrict__ C, unsigned short* __restrict__ hb)
{
    int bid = blockIdx.x;
    int mt = bid >> 2, nt = bid & 3;
    int row0 = mt*64, col0 = nt*128;

    __shared__ __align__(16) unsigned short As[64*40];
    __shared__ __align__(16) unsigned short Bs[128*40];

    int tid = threadIdx.x;
    int wid = tid >> 6, l = tid & 63;
    int wm = wid >> 1, wn = wid & 1;

    f32x4 acc[2][4] = {};
    int ar = tid >> 2, akq = tid & 3;
    for (int k0 = 0; k0 < 256; k0 += 32){
        *(uint4*)&As[ar*40 + akq*8]      = *(const uint4*)&xb[(size_t)(row0+ar)*256 + k0 + akq*8];
        *(uint4*)&Bs[ar*40 + akq*8]      = *(const uint4*)&ewt[(size_t)(col0+ar)*256 + k0 + akq*8];
        *(uint4*)&Bs[(ar+64)*40 + akq*8] = *(const uint4*)&ewt[(size_t)(col0+ar+64)*256 + k0 + akq*8];
        __syncthreads();
        short8v a0 = *(const short8v*)&As[(wm*32 + (l&15))*40 + (l>>4)*8];
        short8v a1 = *(const short8v*)&As[(wm*32 + 16 + (l&15))*40 + (l>>4)*8];
        #pragma unroll
        for (int nj = 0; nj < 4; nj++){
            short8v b = *(const short8v*)&Bs[(wn*64 + nj*16 + (l&15))*40 + (l>>4)*8];
            acc[0][nj] = __builtin_amdgcn_mfma_f32_16x16x32_bf16(a0, b, acc[0][nj], 0, 0, 0);
            acc[1][nj] = __builtin_amdgcn_mfma_f32_16x16x32_bf16(a1, b, acc[1][nj], 0, 0, 0);
        }
        __syncthreads();
    }
    int rbase = (l >> 4)*4, cl = l & 15;
    #pragma unroll
    for (int mi = 0; mi < 2; mi++)
        #pragma unroll
        for (int nj = 0; nj < 4; nj++)
            #pragma unroll
            for (int r = 0; r < 4; r++){
                int grow = row0 + wm*32 + mi*16 + rbase + r;
                int gcol = col0 + wn*64 + nj*16 + cl;
                if (grow < NN){
                    float v = acc[mi][nj][r] + bias[gcol] + pe[(size_t)grow*512 + gcol];
                    C[(size_t)grow*512 + gcol] = v;
                    hb[(size_t)grow*512 + gcol] = f2bf(v);
                }
            }
}

// ---------------- bf16 MFMA GEMM, BK=64: {Q,K,V,S} = h @ W^T + bias ----------------
__global__ __launch_bounds__(256) void gemm_qkvs_mfma(
    const unsigned short* __restrict__ hb,   // [1024][512] bf16
    const unsigned short* __restrict__ Wt,   // [4][512(n)][512(k)] bf16 (this layer)
    const float* __restrict__ qb, const float* __restrict__ kb,
    const float* __restrict__ vb, const float* __restrict__ sb,
    float* __restrict__ Q, float* __restrict__ K,
    float* __restrict__ V, float* __restrict__ S)
{
    int bid = blockIdx.x;
    int mat = bid >> 6;
    int rem = bid & 63;
    int mt = rem >> 2, nt = rem & 3;
    int row0 = mt*64, col0 = nt*128;
    const unsigned short* W = Wt + (size_t)mat*512*512;
    const float* bias = (mat==0)?qb:(mat==1)?kb:(mat==2)?vb:sb;
    float* C = (mat==0)?Q:(mat==1)?K:(mat==2)?V:S;

    __shared__ __align__(16) unsigned short As[64*72];    // BK=64, pad to 72
    __shared__ __align__(16) unsigned short Bs[128*72];

    int tid = threadIdx.x;
    int wid = tid >> 6, l = tid & 63;
    int wm = wid >> 1, wn = wid & 1;

    f32x4 acc[2][4] = {};
    int ar = tid >> 2, ac = tid & 3;     // A: 64 rows x 4 chunks(16 ushorts)
    int br = tid >> 1, bc = tid & 1;     // B: 128 rows x 2 chunks(32 ushorts)
    for (int k0 = 0; k0 < 512; k0 += 64){
        *(uint4*)&As[ar*72 + ac*16 + 0] = *(const uint4*)&hb[(size_t)(row0+ar)*512 + k0 + ac*16 + 0];
        *(uint4*)&As[ar*72 + ac*16 + 8] = *(const uint4*)&hb[(size_t)(row0+ar)*512 + k0 + ac*16 + 8];
        #pragma unroll
        for (int j = 0; j < 4; j++)
            *(uint4*)&Bs[br*72 + bc*32 + j*8] = *(const uint4*)&W[(size_t)(col0+br)*512 + k0 + bc*32 + j*8];
        __syncthreads();
        #pragma unroll
        for (int ks = 0; ks < 64; ks += 32){
            short8v a0 = *(const short8v*)&As[(wm*32 + (l&15))*72 + ks + (l>>4)*8];
            short8v a1 = *(const short8v*)&As[(wm*32 + 16 + (l&15))*72 + ks + (l>>4)*8];
            #pragma unroll
            for (int nj = 0; nj < 4; nj++){
                short8v b = *(const short8v*)&Bs[(wn*64 + nj*16 + (l&15))*72 + ks + (l>>4)*8];
                acc[0][nj] = __builtin_amdgcn_mfma_f32_16x16x32_bf16(a0, b, acc[0][nj], 0, 0, 0);
                acc[1][nj] = __builtin_amdgcn_mfma_f32_16x16x32_bf16(a1, b, acc[1][nj], 0, 0, 0);
            }
        }
        __syncthreads();
    }
    int rbase = (l >> 4)*4, cl = l & 15;
    #pragma unroll
    for (int mi = 0; mi < 2; mi++)
        #pragma unroll
        for (int nj = 0; nj < 4; nj++)
            #pragma unroll
            for (int r = 0; r < 4; r++){
                int grow = row0 + wm*32 + mi*16 + rbase + r;
                int gcol = col0 + wn*64 + nj*16 + cl;
                if (grow < NN) C[(size_t)grow*512 + gcol] = acc[mi][nj][r] + bias[gcol];
            }
}

// ------------- fused per-node attention + skip + LayerNorm (crew-coalesced) -------------
// 512 threads/block, one block per target node.
// Pass 1: 16 crews of 32 lanes; crew reads one K row fully coalesced; per-head dot closed
//         by shfl_xor(1,2); ef staged to LDS as bf16.
// Pass 2: V via float4 x 4 edge-groups; e-accumulate entirely from LDS.
__global__ __launch_bounds__(512) void attn_layer(
    const float* __restrict__ hcur,
    const float* __restrict__ Qm, const float* __restrict__ Km,
    const float* __restrict__ Vm, const float* __restrict__ SKm,
    const float* __restrict__ efs, const float* __restrict__ e_w_l,
    const float* __restrict__ ln_g_l, const float* __restrict__ ln_b_l,
    const int* __restrict__ ssrc, const int* __restrict__ offs,
    float* __restrict__ hnext, unsigned short* __restrict__ hbn)
{
    int tid = threadIdx.x;
    int t = blockIdx.x;

    __shared__ float q_s[8*68];
    __shared__ float qe_s[8*36];
    __shared__ float sc_s[MAXDEG*8];
    __shared__ __align__(8) unsigned short efb_s[MAXDEG*32];
    __shared__ int   src_s[MAXDEG];
    __shared__ float pv_s[2048];
    __shared__ float pe_s[512];
    __shared__ float s_s[256];
    __shared__ float red[64], red2[64];
    __shared__ float m_s[8], d_s[8];

    q_s[(tid>>6)*68 + (tid&63)] = Qm[(size_t)t*512 + tid];
    __syncthreads();
    if (tid < 256){
        int hh = tid>>5, dd = tid&31;
        const float* wrow = e_w_l + (size_t)dd*512 + hh*64;
        const float* qh = q_s + hh*68;
        float a = 0.f;
        #pragma unroll
        for (int c = 0; c < 64; c++) a += qh[c]*wrow[c];
        qe_s[hh*36 + dd] = a;
    }
    int start = offs[t], deg = offs[t+1] - start;
    __syncthreads();

    // ---- pass 1: scores (crew per edge, coalesced K) ----
    int cw = tid >> 5, l = tid & 31;
    int h = l >> 2, sub = l & 3;
    const float4* qp4  = (const float4*)(q_s + h*68 + sub*16);
    const float4* qep4 = (const float4*)(qe_s + h*36 + sub*8);
    float4 qa0 = qp4[0], qa1 = qp4[1], qa2 = qp4[2], qa3 = qp4[3];
    float4 qe0 = qep4[0], qe1 = qep4[1];
    float lmax = -1e30f;
    for (int i = cw; i < deg; i += 16){
        int s = ssrc[start + i];
        if (l == 0) src_s[i] = s;
        const float4* kr = (const float4*)(Km + (size_t)s*512 + l*16);
        const float4* er = (const float4*)(efs + (size_t)(start+i)*32);
        float4 k0 = kr[0], k1 = kr[1], k2 = kr[2], k3 = kr[3];
        float4 e0 = er[sub*2], e1 = er[sub*2+1];
        float p;
        p  = qa0.x*k0.x + qa0.y*k0.y + qa0.z*k0.z + qa0.w*k0.w;
        p += qa1.x*k1.x + qa1.y*k1.y + qa1.z*k1.z + qa1.w*k1.w;
        p += qa2.x*k2.x + qa2.y*k2.y + qa2.z*k2.z + qa2.w*k2.w;
        p += qa3.x*k3.x + qa3.y*k3.y + qa3.z*k3.z + qa3.w*k3.w;
        p += qe0.x*e0.x + qe0.y*e0.y + qe0.z*e0.z + qe0.w*e0.w;
        p += qe1.x*e1.x + qe1.y*e1.y + qe1.z*e1.z + qe1.w*e1.w;
        p += __shfl_xor(p, 1);
        p += __shfl_xor(p, 2);
        p *= SCALE;
        lmax = fmaxf(lmax, p);
        if (sub == 0) sc_s[i*8 + h] = p;
        if (l < 8){
            float4 ev = er[l];
            ushort4 ub;
            ub.x = f2bf(ev.x); ub.y = f2bf(ev.y); ub.z = f2bf(ev.z); ub.w = f2bf(ev.w);
            *(ushort4*)&efb_s[i*32 + l*4] = ub;
        }
    }
    lmax = fmaxf(lmax, __shfl_xor(lmax, 32));
    if (((tid & 63) < 32) && sub == 0) red[(tid>>6)*8 + h] = lmax;
    __syncthreads();
    if (tid < 8){
        float m = red[tid];
        #pragma unroll
        for (int w = 1; w < 8; w++) m = fmaxf(m, red[w*8 + tid]);
        m_s[tid] = m;
    }
    __syncthreads();

    // ---- exp sweep + denominator ----
    {
        int he = tid & 7, ie = tid >> 3;
        float mh = m_s[he];
        float den = 0.f;
        for (int i = ie; i < deg; i += 64){
            float al = __expf(sc_s[i*8 + he] - mh);
            sc_s[i*8 + he] = al;
            den += al;
        }
        den += __shfl_xor(den, 8);
        den += __shfl_xor(den, 16);
        den += __shfl_xor(den, 32);
        if ((tid & 63) < 8) red2[(tid>>6)*8 + (tid & 7)] = den;
    }
    __syncthreads();
    if (tid < 8){
        float d = 0.f;
        #pragma unroll
        for (int w = 0; w < 8; w++) d += red2[w*8 + tid];
        d_s[tid] = d;
    }
    __syncthreads();

    // ---- pass 2a: V accumulation (float4, 4 edge-groups) ----
    {
        int c4 = tid & 127, g = tid >> 7;
        int h2 = c4 >> 4;
        float4 acc = make_float4(0.f, 0.f, 0.f, 0.f);
        const float4* Vm4 = (const float4*)Vm;
        #pragma unroll 4
        for (int i = g; i < deg; i += 4){
            int s = src_s[i];
            float al = sc_s[i*8 + h2];
            float4 v = Vm4[(size_t)s*128 + c4];
            acc.x += al*v.x; acc.y += al*v.y; acc.z += al*v.z; acc.w += al*v.w;
        }
        *(float4*)&pv_s[g*512 + c4*4] = acc;
    }
    // ---- pass 2b: e accumulation (LDS only) ----
    {
        int c2 = tid & 255, g2 = tid >> 8;
        int h3 = c2 >> 5, dd3 = c2 & 31;
        float accE = 0.f;
        #pragma unroll 8
        for (int i = g2; i < deg; i += 2){
            float al = sc_s[i*8 + h3];
            float ev = __uint_as_float(((unsigned)efb_s[i*32 + dd3]) << 16);
            accE += al * ev;
        }
        pe_s[g2*256 + c2] = accE;
    }
    __syncthreads();
    if (tid < 256){
        float dv = d_s[tid>>5];
        float invd = (dv > 0.f) ? 1.f/dv : 0.f;
        s_s[tid] = (pe_s[tid] + pe_s[256+tid]) * invd;
    }
    __syncthreads();

    int c = tid;
    int hh2 = c >> 6;
    float dv = d_s[hh2];
    float invd = (dv > 0.f) ? 1.f/dv : 0.f;
    float vtot = pv_s[c] + pv_s[512+c] + pv_s[1024+c] + pv_s[1536+c];
    float r = vtot * invd;
    float oe = 0.f;
    const float* sp = s_s + hh2*32;
    #pragma unroll
    for (int d = 0; d < 32; d++) oe += sp[d]*e_w_l[(size_t)d*512 + c];
    float x = r + oe + SKm[(size_t)t*512 + c] + hcur[(size_t)t*512 + c];

    // LayerNorm over 512
    int wv = tid >> 6, ln = tid & 63;
    float sA = x, sB = x*x;
    #pragma unroll
    for (int m2 = 1; m2 <= 32; m2 <<= 1){
        sA += __shfl_xor(sA, m2);
        sB += __shfl_xor(sB, m2);
    }
    if (ln == 0){ red[wv] = sA; red2[wv] = sB; }
    __syncthreads();
    float tot = 0.f, tot2 = 0.f;
    #pragma unroll
    for (int w = 0; w < 8; w++){ tot += red[w]; tot2 += red2[w]; }
    float mu  = tot*(1.f/512.f);
    float var = tot2*(1.f/512.f) - mu*mu;
    float rstd = rsqrtf(var + 1e-5f);
    float y = (x - mu)*rstd*ln_g_l[c] + ln_b_l[c];
    hnext[(size_t)t*512 + c] = y;
    hbn[(size_t)t*512 + c]   = f2bf(y);
}

// ---------------- final head: dom + concat + MLP ----------------
__global__ __launch_bounds__(256) void final_head(
    const float* __restrict__ hin,
    const float* __restrict__ dom_w, const float* __restrict__ dom_b,
    const float* __restrict__ w1, const float* __restrict__ b1,
    const float* __restrict__ w2, const float* __restrict__ b2,
    float* __restrict__ out)
{
    int tid = threadIdx.x, t = blockIdx.x;
    __shared__ float h_s[512];
    __shared__ float dom_s[16];
    __shared__ float hid_s[256];
    __shared__ float red[256];
    h_s[tid]     = hin[(size_t)t*512 + tid];
    h_s[tid+256] = hin[(size_t)t*512 + 256 + tid];
    __syncthreads();
    if (tid < 16){
        float a = dom_b[tid];
        for (int i = 0; i < 512; i++) a += h_s[i]*dom_w[i*16 + tid];
        dom_s[tid] = a;
    }
    __syncthreads();
    float acc = b1[tid];
    for (int i = 0; i < 512; i++) acc += h_s[i]*w1[(size_t)i*256 + tid];
    #pragma unroll
    for (int i = 0; i < 16; i++) acc += dom_s[i]*w1[(size_t)(512+i)*256 + tid];
    hid_s[tid] = fmaxf(acc, 0.f);
    __syncthreads();
    int o = tid & 15, g = tid >> 4;
    float p = 0.f;
    #pragma unroll
    for (int j = 0; j < 16; j++) p += hid_s[g*16 + j]*w2[(g*16 + j)*16 + o];
    red[tid] = p;
    __syncthreads();
    if (tid < 16){
        float s2 = b2[tid];
        for (int gg = 0; gg < 16; gg++) s2 += red[gg*16 + tid];
        out[(size_t)t*16 + tid] = s2;
    }
}

// ---------------- launch ----------------
extern "C" void kernel_launch(void* const* d_in, const int* in_sizes, int n_in,
                              void* d_out, int out_size, void* d_ws, size_t ws_size,
                              hipStream_t stream)
{
    const float* x       = (const float*)d_in[0];
    const int*   eidx    = (const int*)  d_in[1];
    const float* eattr   = (const float*)d_in[2];
    const float* embed_w = (const float*)d_in[3];
    const float* embed_b = (const float*)d_in[4];
    const float* pe      = (const float*)d_in[5];
    const float* ee_w1   = (const float*)d_in[6];
    const float* ee_b1   = (const float*)d_in[7];
    const float* ee_w2   = (const float*)d_in[8];
    const float* ee_b2   = (const float*)d_in[9];
    const float* q_w     = (const float*)d_in[10];
    const float* q_b     = (const float*)d_in[11];
    const float* k_w     = (const float*)d_in[12];
    const float* k_b     = (const float*)d_in[13];
    const float* v_w     = (const float*)d_in[14];
    const float* v_b     = (const float*)d_in[15];
    const float* e_w     = (const float*)d_in[16];
    const float* skip_w  = (const float*)d_in[17];
    const float* skip_b  = (const float*)d_in[18];
    const float* ln_g    = (const float*)d_in[19];
    const float* ln_b    = (const float*)d_in[20];
    const float* dom_w   = (const float*)d_in[21];
    const float* dom_b   = (const float*)d_in[22];
    const float* cls_w1  = (const float*)d_in[23];
    const float* cls_b1  = (const float*)d_in[24];
    const float* cls_w2  = (const float*)d_in[25];
    const float* cls_b2  = (const float*)d_in[26];
    float* out = (float*)d_out;

    float* ws = (float*)d_ws;
    size_t o = 0;
    float* h0    = ws + o; o += (size_t)512*NN;
    float* h1    = ws + o; o += (size_t)512*NN;
    float* Qb    = ws + o; o += (size_t)512*NN;
    float* Kb    = ws + o; o += (size_t)512*NN;
    float* Vb    = ws + o; o += (size_t)512*NN;
    float* Sb    = ws + o; o += (size_t)512*NN;
    float* efs   = ws + o; o += (size_t)32*EE;
    unsigned short* hb  = (unsigned short*)(ws + o); o += (size_t)1024*512/2;
    unsigned short* xb  = (unsigned short*)(ws + o); o += (size_t)1024*256/2;
    unsigned short* ewt = (unsigned short*)(ws + o); o += (size_t)512*256/2;
    unsigned short* Wtb = (unsigned short*)(ws + o); o += (size_t)24*512*512/2;
    int* cnt    = (int*)(ws + o); o += 1024;
    int* offs   = (int*)(ws + o); o += 1024;
    int* cursor = (int*)(ws + o); o += 1024;
    int* ssrc   = (int*)(ws + o); o += EE;
    int* epos   = (int*)(ws + o); o += EE;

    const int* srcp = eidx;
    const int* tgtp = eidx + EE;

    zero_counts<<<1, 1024, 0, stream>>>(cnt);
    hist_kernel<<<EE/256, 256, 0, stream>>>(tgtp, cnt);
    scan_kernel<<<1, 1024, 0, stream>>>(cnt, offs, cursor);
    scatter_kernel<<<EE/256, 256, 0, stream>>>(srcp, tgtp, cursor, ssrc, epos);
    edge_enc<<<EE/256, 256, 0, stream>>>(eattr, ee_w1, ee_b1, ee_w2, ee_b2, epos, efs);
    convert_x<<<1024, 256, 0, stream>>>(x, xb);
    tconv<<<dim3(512/32, 256/32), 256, 0, stream>>>(embed_w, ewt, 256, 512);
    tconv24<<<24*256, 256, 0, stream>>>(q_w, k_w, v_w, skip_w, Wtb);
    gemm_embed_mfma<<<64, 256, 0, stream>>>(xb, ewt, embed_b, pe, h0, hb);

    float* hc = h0;
    float* hn = h1;
    for (int l = 0; l < LAYERS; l++){
        gemm_qkvs_mfma<<<256, 256, 0, stream>>>(
            hb, Wtb + (size_t)l*4*512*512,
            q_b + (size_t)l*512, k_b + (size_t)l*512,
            v_b + (size_t)l*512, skip_b + (size_t)l*512,
            Qb, Kb, Vb, Sb);
        attn_layer<<<NN, 512, 0, stream>>>(
            hc, Qb, Kb, Vb, Sb, efs, e_w + (size_t)l*32*512,
            ln_g + (size_t)l*512, ln_b + (size_t)l*512,
            ssrc, offs, hn, hb);
        float* tmp = hc; hc = hn; hn = tmp;
    }
    final_head<<<NN, 256, 0, stream>>>(hc, dom_w, dom_b, cls_w1, cls_b1, cls_w2, cls_b2, out);
}

// Round 6
// 581.135 us; speedup vs baseline: 1.9880x; 1.1773x over previous
//
#include <hip/hip_runtime.h>
#include <hip/hip_bf16.h>
#include <cstdint>
#include <cstddef>

#define NN 1000
#define EE 128000
#define LAYERS 6
#define SCALE 0.125f
#define MAXDEG 320

typedef __attribute__((ext_vector_type(4))) float f32x4;
typedef __attribute__((ext_vector_type(8))) short short8v;

static __device__ __forceinline__ unsigned short f2bf(float x){
    unsigned int u = __float_as_uint(x);
    unsigned int lsb = (u >> 16) & 1u;
    u += 0x7fffu + lsb;
    return (unsigned short)(u >> 16);
}
static __device__ __forceinline__ float bf2f(unsigned short u){
    return __uint_as_float(((unsigned int)u) << 16);
}

// ---------------- sort-by-target (counting sort) ----------------
__global__ void zero_counts(int* cnt){
    cnt[threadIdx.x] = 0;
}

__global__ void hist_kernel(const int* __restrict__ tgt, int* cnt){
    int e = blockIdx.x*256 + threadIdx.x;
    if (e < EE) atomicAdd(&cnt[tgt[e]], 1);
}

__global__ void scan_kernel(const int* __restrict__ cnt, int* offs, int* cursor){
    __shared__ int s[1024];
    int tid = threadIdx.x;
    s[tid] = (tid < NN) ? cnt[tid] : 0;
    __syncthreads();
    for (int st = 1; st < 1024; st <<= 1){
        int v = (tid >= st) ? s[tid-st] : 0;
        __syncthreads();
        s[tid] += v;
        __syncthreads();
    }
    int excl = (tid == 0) ? 0 : s[tid-1];
    if (tid < NN){ offs[tid] = excl; cursor[tid] = excl; }
    if (tid == 0) offs[NN] = s[NN-1];
}

__global__ void scatter_kernel(const int* __restrict__ src, const int* __restrict__ tgt,
                               int* cursor, int* ssrc, int* epos){
    int e = blockIdx.x*256 + threadIdx.x;
    if (e < EE){
        int t = tgt[e];
        int pos = atomicAdd(&cursor[t], 1);
        ssrc[pos] = src[e];
        epos[e] = pos;
    }
}

// ---------------- edge encoder: 4 -> 16 -> 32, bf16 out, sorted order ----------------
__global__ __launch_bounds__(256) void edge_enc(
    const float* __restrict__ edge_attr,
    const float* __restrict__ w1, const float* __restrict__ b1,
    const float* __restrict__ w2, const float* __restrict__ b2,
    const int* __restrict__ epos,
    unsigned short* __restrict__ efs)
{
    __shared__ float w1s[64], b1s[16], w2s[512], b2s[32];
    int tid = threadIdx.x;
    if (tid < 64) w1s[tid] = w1[tid];
    if (tid < 16) b1s[tid] = b1[tid];
    if (tid < 32) b2s[tid] = b2[tid];
    w2s[tid] = w2[tid];
    w2s[tid+256] = w2[tid+256];
    __syncthreads();
    int e = blockIdx.x*256 + tid;
    if (e >= EE) return;
    float4 av = *(const float4*)(edge_attr + (size_t)e*4);
    float hd[16];
    #pragma unroll
    for (int i = 0; i < 16; i++){
        float v = av.x*w1s[i] + av.y*w1s[16+i] + av.z*w1s[32+i] + av.w*w1s[48+i] + b1s[i];
        hd[i] = fmaxf(v, 0.f);
    }
    unsigned short* op = efs + (size_t)epos[e]*32;
    #pragma unroll
    for (int k4 = 0; k4 < 8; k4++){
        ushort4 ub;
        float v0 = b2s[k4*4+0], v1 = b2s[k4*4+1], v2 = b2s[k4*4+2], v3 = b2s[k4*4+3];
        #pragma unroll
        for (int i = 0; i < 16; i++){
            float hv = hd[i];
            v0 += hv*w2s[i*32 + k4*4+0];
            v1 += hv*w2s[i*32 + k4*4+1];
            v2 += hv*w2s[i*32 + k4*4+2];
            v3 += hv*w2s[i*32 + k4*4+3];
        }
        ub.x = f2bf(v0); ub.y = f2bf(v1); ub.z = f2bf(v2); ub.w = f2bf(v3);
        *(ushort4*)(op + k4*4) = ub;
    }
}

// ---------------- x -> bf16 (zero-pad rows >= NN) ----------------
__global__ __launch_bounds__(256) void convert_x(const float* __restrict__ x, unsigned short* __restrict__ xb){
    int row = blockIdx.x;
    int c = threadIdx.x;
    xb[(size_t)row*256 + c] = (row < NN) ? f2bf(x[(size_t)row*256 + c]) : (unsigned short)0;
}

// ---------------- transpose-convert: dst[n][k] = bf16(src[k][n]) ----------------
__global__ __launch_bounds__(256) void tconv(const float* __restrict__ src, unsigned short* __restrict__ dst,
                                             int Kk, int Nn){
    int tn = blockIdx.x, tk = blockIdx.y;
    __shared__ float ts[32][33];
    int tid = threadIdx.x;
    int r = tid >> 3, c0 = (tid & 7)*4;
    float4 v = *(const float4*)(src + (size_t)(tk*32 + r)*Nn + tn*32 + c0);
    ts[r][c0+0] = v.x; ts[r][c0+1] = v.y; ts[r][c0+2] = v.z; ts[r][c0+3] = v.w;
    __syncthreads();
    ushort4 o;
    o.x = f2bf(ts[c0+0][r]); o.y = f2bf(ts[c0+1][r]);
    o.z = f2bf(ts[c0+2][r]); o.w = f2bf(ts[c0+3][r]);
    *(ushort4*)(dst + (size_t)(tn*32 + r)*Kk + tk*32 + c0) = o;
}

__global__ __launch_bounds__(256) void tconv24(
    const float* __restrict__ Wq, const float* __restrict__ Wk,
    const float* __restrict__ Wv, const float* __restrict__ Ws,
    unsigned short* __restrict__ Wt)
{
    int bid = blockIdx.x;
    int mm = bid >> 8;
    int tile = bid & 255;
    int tk = tile >> 4, tn = tile & 15;
    int l = mm >> 2, m = mm & 3;
    const float* W = ((m==0)?Wq:(m==1)?Wk:(m==2)?Wv:Ws) + (size_t)l*512*512;
    unsigned short* dst = Wt + (size_t)mm*512*512;
    __shared__ float ts[32][33];
    int tid = threadIdx.x;
    int r = tid >> 3, c0 = (tid & 7)*4;
    float4 v = *(const float4*)(W + (size_t)(tk*32 + r)*512 + tn*32 + c0);
    ts[r][c0+0] = v.x; ts[r][c0+1] = v.y; ts[r][c0+2] = v.z; ts[r][c0+3] = v.w;
    __syncthreads();
    ushort4 o;
    o.x = f2bf(ts[c0+0][r]); o.y = f2bf(ts[c0+1][r]);
    o.z = f2bf(ts[c0+2][r]); o.w = f2bf(ts[c0+3][r]);
    *(ushort4*)(dst + (size_t)(tn*32 + r)*512 + tk*32 + c0) = o;
}

// ---------------- MFMA embed GEMM: h0 = x@W + b + pe (K=256), fp32 + bf16 out ----------------
__global__ __launch_bounds__(256) void gemm_embed_mfma(
    const unsigned short* __restrict__ xb,
    const unsigned short* __restrict__ ewt,
    const float* __restrict__ bias, const float* __restrict__ pe,
    float* __restrict__ C, unsigned short* __restrict__ hb)
{
    int bid = blockIdx.x;
    int mt = bid >> 2, nt = bid & 3;
    int row0 = mt*64, col0 = nt*128;

    __shared__ __align__(16) unsigned short As[64*40];
    __shared__ __align__(16) unsigned short Bs[128*40];

    int tid = threadIdx.x;
    int wid = tid >> 6, l = tid & 63;
    int wm = wid >> 1, wn = wid & 1;

    f32x4 acc[2][4] = {};
    int ar = tid >> 2, akq = tid & 3;
    for (int k0 = 0; k0 < 256; k0 += 32){
        *(uint4*)&As[ar*40 + akq*8]      = *(const uint4*)&xb[(size_t)(row0+ar)*256 + k0 + akq*8];
        *(uint4*)&Bs[ar*40 + akq*8]      = *(const uint4*)&ewt[(size_t)(col0+ar)*256 + k0 + akq*8];
        *(uint4*)&Bs[(ar+64)*40 + akq*8] = *(const uint4*)&ewt[(size_t)(col0+ar+64)*256 + k0 + akq*8];
        __syncthreads();
        short8v a0 = *(const short8v*)&As[(wm*32 + (l&15))*40 + (l>>4)*8];
        short8v a1 = *(const short8v*)&As[(wm*32 + 16 + (l&15))*40 + (l>>4)*8];
        #pragma unroll
        for (int nj = 0; nj < 4; nj++){
            short8v b = *(const short8v*)&Bs[(wn*64 + nj*16 + (l&15))*40 + (l>>4)*8];
            acc[0][nj] = __builtin_amdgcn_mfma_f32_16x16x32_bf16(a0, b, acc[0][nj], 0, 0, 0);
            acc[1][nj] = __builtin_amdgcn_mfma_f32_16x16x32_bf16(a1, b, acc[1][nj], 0, 0, 0);
        }
        __syncthreads();
    }
    int rbase = (l >> 4)*4, cl = l & 15;
    #pragma unroll
    for (int mi = 0; mi < 2; mi++)
        #pragma unroll
        for (int nj = 0; nj < 4; nj++)
            #pragma unroll
            for (int r = 0; r < 4; r++){
                int grow = row0 + wm*32 + mi*16 + rbase + r;
                int gcol = col0 + wn*64 + nj*16 + cl;
                if (grow < NN){
                    float v = acc[mi][nj][r] + bias[gcol] + pe[(size_t)grow*512 + gcol];
                    C[(size_t)grow*512 + gcol] = v;
                    hb[(size_t)grow*512 + gcol] = f2bf(v);
                }
            }
}

// ---------------- bf16 MFMA GEMM, 64x64 tiles, reg-prefetch ----------------
// Q,S -> fp32; K,V -> bf16. grid = 4 mats x 16 mtiles x 8 ntiles = 512 blocks.
__global__ __launch_bounds__(256) void gemm_qkvs_mfma(
    const unsigned short* __restrict__ hb,   // [1024][512] bf16
    const unsigned short* __restrict__ Wt,   // [4][512(n)][512(k)] bf16 (this layer)
    const float* __restrict__ qb, const float* __restrict__ kb,
    const float* __restrict__ vb, const float* __restrict__ sb,
    float* __restrict__ Q, unsigned short* __restrict__ K16,
    unsigned short* __restrict__ V16, float* __restrict__ S)
{
    int bid = blockIdx.x;
    int mat = bid >> 7;
    int rem = bid & 127;
    int mt = rem >> 3, nt = rem & 7;
    int row0 = mt*64, col0 = nt*64;
    const unsigned short* W = Wt + (size_t)mat*512*512;
    const float* bias = (mat==0)?qb:(mat==1)?kb:(mat==2)?vb:sb;

    __shared__ __align__(16) unsigned short As[64*72];
    __shared__ __align__(16) unsigned short Bs[64*72];

    int tid = threadIdx.x;
    int wid = tid >> 6, l = tid & 63;
    int wm = wid >> 1, wn = wid & 1;

    f32x4 acc[2][2] = {};
    int lr = tid >> 2;            // 64 rows
    int lc = (tid & 3)*2;         // chunk pairs: 0,2,4,6 (each chunk = 8 ushorts)
    const unsigned short* ga = hb + (size_t)(row0+lr)*512 + lc*8;
    const unsigned short* gb = W  + (size_t)(col0+lr)*512 + lc*8;

    uint4 ra0 = *(const uint4*)(ga);
    uint4 ra1 = *(const uint4*)(ga + 8);
    uint4 rb0 = *(const uint4*)(gb);
    uint4 rb1 = *(const uint4*)(gb + 8);

    for (int k0 = 0; k0 < 512; k0 += 64){
        __syncthreads();
        *(uint4*)&As[lr*72 + lc*8]     = ra0;
        *(uint4*)&As[lr*72 + lc*8 + 8] = ra1;
        *(uint4*)&Bs[lr*72 + lc*8]     = rb0;
        *(uint4*)&Bs[lr*72 + lc*8 + 8] = rb1;
        __syncthreads();
        if (k0 + 64 < 512){
            ra0 = *(const uint4*)(ga + k0 + 64);
            ra1 = *(const uint4*)(ga + k0 + 72);
            rb0 = *(const uint4*)(gb + k0 + 64);
            rb1 = *(const uint4*)(gb + k0 + 72);
        }
        #pragma unroll
        for (int ks = 0; ks < 2; ks++){
            short8v a0 = *(const short8v*)&As[(wm*32 + (l&15))*72      + ks*32 + (l>>4)*8];
            short8v a1 = *(const short8v*)&As[(wm*32 + 16 + (l&15))*72 + ks*32 + (l>>4)*8];
            short8v b0 = *(const short8v*)&Bs[(wn*32 + (l&15))*72      + ks*32 + (l>>4)*8];
            short8v b1 = *(const short8v*)&Bs[(wn*32 + 16 + (l&15))*72 + ks*32 + (l>>4)*8];
            acc[0][0] = __builtin_amdgcn_mfma_f32_16x16x32_bf16(a0, b0, acc[0][0], 0, 0, 0);
            acc[0][1] = __builtin_amdgcn_mfma_f32_16x16x32_bf16(a0, b1, acc[0][1], 0, 0, 0);
            acc[1][0] = __builtin_amdgcn_mfma_f32_16x16x32_bf16(a1, b0, acc[1][0], 0, 0, 0);
            acc[1][1] = __builtin_amdgcn_mfma_f32_16x16x32_bf16(a1, b1, acc[1][1], 0, 0, 0);
        }
    }
    int rbase = (l >> 4)*4, cl = l & 15;
    #pragma unroll
    for (int mi = 0; mi < 2; mi++)
        #pragma unroll
        for (int nj = 0; nj < 2; nj++)
            #pragma unroll
            for (int r = 0; r < 4; r++){
                int grow = row0 + wm*32 + mi*16 + rbase + r;
                int gcol = col0 + wn*32 + nj*16 + cl;
                if (grow < NN){
                    float v = acc[mi][nj][r] + bias[gcol];
                    if (mat == 0)      Q[(size_t)grow*512 + gcol] = v;
                    else if (mat == 1) K16[(size_t)grow*512 + gcol] = f2bf(v);
                    else if (mat == 2) V16[(size_t)grow*512 + gcol] = f2bf(v);
                    else               S[(size_t)grow*512 + gcol] = v;
                }
            }
}

// ------------- fused per-node attention + skip + LayerNorm (bf16 K/V/ef) -------------
// 512 threads/block, one block per target node; ~27 KB LDS -> all 1000 blocks co-resident.
__global__ __launch_bounds__(512) void attn_layer(
    const float* __restrict__ hcur,
    const float* __restrict__ Qm, const unsigned short* __restrict__ Km,
    const unsigned short* __restrict__ Vm, const float* __restrict__ SKm,
    const unsigned short* __restrict__ efs, const float* __restrict__ e_w_l,
    const float* __restrict__ ln_g_l, const float* __restrict__ ln_b_l,
    const int* __restrict__ ssrc, const int* __restrict__ offs,
    float* __restrict__ hnext, unsigned short* __restrict__ hbn)
{
    int tid = threadIdx.x;
    int t = blockIdx.x;

    __shared__ float q_s[8*68];
    __shared__ float qe_s[8*36];
    __shared__ float sc_s[MAXDEG*8];
    __shared__ int   src_s[MAXDEG];
    __shared__ float pv_s[2048];
    __shared__ float pe_s[512];
    __shared__ float s_s[256];
    __shared__ float red[64], red2[64];
    __shared__ float m_s[8], d_s[8];

    q_s[(tid>>6)*68 + (tid&63)] = Qm[(size_t)t*512 + tid];
    __syncthreads();
    if (tid < 256){
        int hh = tid>>5, dd = tid&31;
        const float* wrow = e_w_l + (size_t)dd*512 + hh*64;
        const float* qh = q_s + hh*68;
        float a = 0.f;
        #pragma unroll
        for (int c = 0; c < 64; c++) a += qh[c]*wrow[c];
        qe_s[hh*36 + dd] = a;
    }
    int start = offs[t], deg = offs[t+1] - start;
    __syncthreads();

    // ---- pass 1: scores (crew of 32 per edge, coalesced bf16 K) ----
    int cw = tid >> 5, l = tid & 31;
    int h = l >> 2, sub = l & 3;
    const float4* qp4  = (const float4*)(q_s + h*68 + sub*16);
    const float4* qep4 = (const float4*)(qe_s + h*36 + sub*8);
    float4 qa0 = qp4[0], qa1 = qp4[1], qa2 = qp4[2], qa3 = qp4[3];
    float4 qe0 = qep4[0], qe1 = qep4[1];
    float lmax = -1e30f;
    for (int i = cw; i < deg; i += 16){
        int s = ssrc[start + i];
        if (l == 0) src_s[i] = s;
        const unsigned short* kr = Km + (size_t)s*512 + l*16;
        short8v k0 = *(const short8v*)(kr);
        short8v k1 = *(const short8v*)(kr + 8);
        short8v ev = *(const short8v*)(efs + (size_t)(start+i)*32 + sub*8);
        float p;
        p  = qa0.x*bf2f((unsigned short)k0[0]) + qa0.y*bf2f((unsigned short)k0[1])
           + qa0.z*bf2f((unsigned short)k0[2]) + qa0.w*bf2f((unsigned short)k0[3]);
        p += qa1.x*bf2f((unsigned short)k0[4]) + qa1.y*bf2f((unsigned short)k0[5])
           + qa1.z*bf2f((unsigned short)k0[6]) + qa1.w*bf2f((unsigned short)k0[7]);
        p += qa2.x*bf2f((unsigned short)k1[0]) + qa2.y*bf2f((unsigned short)k1[1])
           + qa2.z*bf2f((unsigned short)k1[2]) + qa2.w*bf2f((unsigned short)k1[3]);
        p += qa3.x*bf2f((unsigned short)k1[4]) + qa3.y*bf2f((unsigned short)k1[5])
           + qa3.z*bf2f((unsigned short)k1[6]) + qa3.w*bf2f((unsigned short)k1[7]);
        p += qe0.x*bf2f((unsigned short)ev[0]) + qe0.y*bf2f((unsigned short)ev[1])
           + qe0.z*bf2f((unsigned short)ev[2]) + qe0.w*bf2f((unsigned short)ev[3]);
        p += qe1.x*bf2f((unsigned short)ev[4]) + qe1.y*bf2f((unsigned short)ev[5])
           + qe1.z*bf2f((unsigned short)ev[6]) + qe1.w*bf2f((unsigned short)ev[7]);
        p += __shfl_xor(p, 1);
        p += __shfl_xor(p, 2);
        p *= SCALE;
        lmax = fmaxf(lmax, p);
        if (sub == 0) sc_s[i*8 + h] = p;
    }
    lmax = fmaxf(lmax, __shfl_xor(lmax, 32));
    if (((tid & 63) < 32) && sub == 0) red[(tid>>6)*8 + h] = lmax;
    __syncthreads();
    if (tid < 8){
        float m = red[tid];
        #pragma unroll
        for (int w = 1; w < 8; w++) m = fmaxf(m, red[w*8 + tid]);
        m_s[tid] = m;
    }
    __syncthreads();

    // ---- exp sweep + denominator ----
    {
        int he = tid & 7, ie = tid >> 3;
        float mh = m_s[he];
        float den = 0.f;
        for (int i = ie; i < deg; i += 64){
            float al = __expf(sc_s[i*8 + he] - mh);
            sc_s[i*8 + he] = al;
            den += al;
        }
        den += __shfl_xor(den, 8);
        den += __shfl_xor(den, 16);
        den += __shfl_xor(den, 32);
        if ((tid & 63) < 8) red2[(tid>>6)*8 + (tid & 7)] = den;
    }
    __syncthreads();
    if (tid < 8){
        float d = 0.f;
        #pragma unroll
        for (int w = 0; w < 8; w++) d += red2[w*8 + tid];
        d_s[tid] = d;
    }
    __syncthreads();

    // ---- pass 2a: V accumulation (bf16 V, 4 edge-groups) ----
    {
        int c4 = tid & 127, g = tid >> 7;
        int h2 = c4 >> 4;
        float4 acc = make_float4(0.f, 0.f, 0.f, 0.f);
        #pragma unroll 4
        for (int i = g; i < deg; i += 4){
            int s = src_s[i];
            float al = sc_s[i*8 + h2];
            ushort4 v = *(const ushort4*)(Vm + (size_t)s*512 + c4*4);
            acc.x += al*bf2f(v.x); acc.y += al*bf2f(v.y);
            acc.z += al*bf2f(v.z); acc.w += al*bf2f(v.w);
        }
        *(float4*)&pv_s[g*512 + c4*4] = acc;
    }
    // ---- pass 2b: e accumulation (bf16 ef from global; L2-hot) ----
    {
        int c2 = tid & 255, g2 = tid >> 8;
        int h3 = c2 >> 5, dd3 = c2 & 31;
        float accE = 0.f;
        #pragma unroll 8
        for (int i = g2; i < deg; i += 2){
            float al = sc_s[i*8 + h3];
            accE += al * bf2f(efs[(size_t)(start+i)*32 + dd3]);
        }
        pe_s[g2*256 + c2] = accE;
    }
    __syncthreads();
    if (tid < 256){
        float dv = d_s[tid>>5];
        float invd = (dv > 0.f) ? 1.f/dv : 0.f;
        s_s[tid] = (pe_s[tid] + pe_s[256+tid]) * invd;
    }
    __syncthreads();

    int c = tid;
    int hh2 = c >> 6;
    float dv = d_s[hh2];
    float invd = (dv > 0.f) ? 1.f/dv : 0.f;
    float vtot = pv_s[c] + pv_s[512+c] + pv_s[1024+c] + pv_s[1536+c];
    float r = vtot * invd;
    float oe = 0.f;
    const float* sp = s_s + hh2*32;
    #pragma unroll
    for (int d = 0; d < 32; d++) oe += sp[d]*e_w_l[(size_t)d*512 + c];
    float x = r + oe + SKm[(size_t)t*512 + c] + hcur[(size_t)t*512 + c];

    // LayerNorm over 512
    int wv = tid >> 6, ln = tid & 63;
    float sA = x, sB = x*x;
    #pragma unroll
    for (int m2 = 1; m2 <= 32; m2 <<= 1){
        sA += __shfl_xor(sA, m2);
        sB += __shfl_xor(sB, m2);
    }
    if (ln == 0){ red[wv] = sA; red2[wv] = sB; }
    __syncthreads();
    float tot = 0.f, tot2 = 0.f;
    #pragma unroll
    for (int w = 0; w < 8; w++){ tot += red[w]; tot2 += red2[w]; }
    float mu  = tot*(1.f/512.f);
    float var = tot2*(1.f/512.f) - mu*mu;
    float rstd = rsqrtf(var + 1e-5f);
    float y = (x - mu)*rstd*ln_g_l[c] + ln_b_l[c];
    hnext[(size_t)t*512 + c] = y;
    hbn[(size_t)t*512 + c]   = f2bf(y);
}

// ---------------- final head: dom + concat + MLP ----------------
__global__ __launch_bounds__(256) void final_head(
    const float* __restrict__ hin,
    const float* __restrict__ dom_w, const float* __restrict__ dom_b,
    const float* __restrict__ w1, const float* __restrict__ b1,
    const float* __restrict__ w2, const float* __restrict__ b2,
    float* __restrict__ out)
{
    int tid = threadIdx.x, t = blockIdx.x;
    __shared__ float h_s[512];
    __shared__ float dom_s[16];
    __shared__ float hid_s[256];
    __shared__ float red[256];
    h_s[tid]     = hin[(size_t)t*512 + tid];
    h_s[tid+256] = hin[(size_t)t*512 + 256 + tid];
    __syncthreads();
    if (tid < 16){
        float a = dom_b[tid];
        for (int i = 0; i < 512; i++) a += h_s[i]*dom_w[i*16 + tid];
        dom_s[tid] = a;
    }
    __syncthreads();
    float acc = b1[tid];
    for (int i = 0; i < 512; i++) acc += h_s[i]*w1[(size_t)i*256 + tid];
    #pragma unroll
    for (int i = 0; i < 16; i++) acc += dom_s[i]*w1[(size_t)(512+i)*256 + tid];
    hid_s[tid] = fmaxf(acc, 0.f);
    __syncthreads();
    int o = tid & 15, g = tid >> 4;
    float p = 0.f;
    #pragma unroll
    for (int j = 0; j < 16; j++) p += hid_s[g*16 + j]*w2[(g*16 + j)*16 + o];
    red[tid] = p;
    __syncthreads();
    if (tid < 16){
        float s2 = b2[tid];
        for (int gg = 0; gg < 16; gg++) s2 += red[gg*16 + tid];
        out[(size_t)t*16 + tid] = s2;
    }
}

// ---------------- launch ----------------
extern "C" void kernel_launch(void* const* d_in, const int* in_sizes, int n_in,
                              void* d_out, int out_size, void* d_ws, size_t ws_size,
                              hipStream_t stream)
{
    const float* x       = (const float*)d_in[0];
    const int*   eidx    = (const int*)  d_in[1];
    const float* eattr   = (const float*)d_in[2];
    const float* embed_w = (const float*)d_in[3];
    const float* embed_b = (const float*)d_in[4];
    const float* pe      = (const float*)d_in[5];
    const float* ee_w1   = (const float*)d_in[6];
    const float* ee_b1   = (const float*)d_in[7];
    const float* ee_w2   = (const float*)d_in[8];
    const float* ee_b2   = (const float*)d_in[9];
    const float* q_w     = (const float*)d_in[10];
    const float* q_b     = (const float*)d_in[11];
    const float* k_w     = (const float*)d_in[12];
    const float* k_b     = (const float*)d_in[13];
    const float* v_w     = (const float*)d_in[14];
    const float* v_b     = (const float*)d_in[15];
    const float* e_w     = (const float*)d_in[16];
    const float* skip_w  = (const float*)d_in[17];
    const float* skip_b  = (const float*)d_in[18];
    const float* ln_g    = (const float*)d_in[19];
    const float* ln_b    = (const float*)d_in[20];
    const float* dom_w   = (const float*)d_in[21];
    const float* dom_b   = (const float*)d_in[22];
    const float* cls_w1  = (const float*)d_in[23];
    const float* cls_b1  = (const float*)d_in[24];
    const float* cls_w2  = (const float*)d_in[25];
    const float* cls_b2  = (const float*)d_in[26];
    float* out = (float*)d_out;

    float* ws = (float*)d_ws;
    size_t o = 0;
    float* h0    = ws + o; o += (size_t)512*NN;
    float* h1    = ws + o; o += (size_t)512*NN;
    float* Qb    = ws + o; o += (size_t)512*NN;
    float* Sb    = ws + o; o += (size_t)512*NN;
    unsigned short* Kb16 = (unsigned short*)(ws + o); o += (size_t)1024*512/2;
    unsigned short* Vb16 = (unsigned short*)(ws + o); o += (size_t)1024*512/2;
    unsigned short* efs  = (unsigned short*)(ws + o); o += (size_t)EE*32/2;
    unsigned short* hb   = (unsigned short*)(ws + o); o += (size_t)1024*512/2;
    unsigned short* xb   = (unsigned short*)(ws + o); o += (size_t)1024*256/2;
    unsigned short* ewt  = (unsigned short*)(ws + o); o += (size_t)512*256/2;
    unsigned short* Wtb  = (unsigned short*)(ws + o); o += (size_t)24*512*512/2;
    int* cnt    = (int*)(ws + o); o += 1024;
    int* offs   = (int*)(ws + o); o += 1024;
    int* cursor = (int*)(ws + o); o += 1024;
    int* ssrc   = (int*)(ws + o); o += EE;
    int* epos   = (int*)(ws + o); o += EE;

    const int* srcp = eidx;
    const int* tgtp = eidx + EE;

    zero_counts<<<1, 1024, 0, stream>>>(cnt);
    hist_kernel<<<EE/256, 256, 0, stream>>>(tgtp, cnt);
    scan_kernel<<<1, 1024, 0, stream>>>(cnt, offs, cursor);
    scatter_kernel<<<EE/256, 256, 0, stream>>>(srcp, tgtp, cursor, ssrc, epos);
    edge_enc<<<EE/256, 256, 0, stream>>>(eattr, ee_w1, ee_b1, ee_w2, ee_b2, epos, efs);
    convert_x<<<1024, 256, 0, stream>>>(x, xb);
    tconv<<<dim3(512/32, 256/32), 256, 0, stream>>>(embed_w, ewt, 256, 512);
    tconv24<<<24*256, 256, 0, stream>>>(q_w, k_w, v_w, skip_w, Wtb);
    gemm_embed_mfma<<<64, 256, 0, stream>>>(xb, ewt, embed_b, pe, h0, hb);

    float* hc = h0;
    float* hn = h1;
    for (int l = 0; l < LAYERS; l++){
        gemm_qkvs_mfma<<<512, 256, 0, stream>>>(
            hb, Wtb + (size_t)l*4*512*512,
            q_b + (size_t)l*512, k_b + (size_t)l*512,
            v_b + (size_t)l*512, skip_b + (size_t)l*512,
            Qb, Kb16, Vb16, Sb);
        attn_layer<<<NN, 512, 0, stream>>>(
            hc, Qb, Kb16, Vb16, Sb, efs, e_w + (size_t)l*32*512,
            ln_g + (size_t)l*512, ln_b + (size_t)l*512,
            ssrc, offs, hn, hb);
        float* tmp = hc; hc = hn; hn = tmp;
    }
    final_head<<<NN, 256, 0, stream>>>(hc, dom_w, dom_b, cls_w1, cls_b1, cls_w2, cls_b2, out);
}

// Round 7
// 551.671 us; speedup vs baseline: 2.0942x; 1.0534x over previous
//
#include <hip/hip_runtime.h>
#include <hip/hip_bf16.h>
#include <cstdint>
#include <cstddef>

#define NN 1000
#define EE 128000
#define LAYERS 6
#define SCALE 0.125f
#define MAXDEG 320

typedef __attribute__((ext_vector_type(4))) float f32x4;
typedef __attribute__((ext_vector_type(8))) short short8v;

static __device__ __forceinline__ unsigned short f2bf(float x){
    unsigned int u = __float_as_uint(x);
    unsigned int lsb = (u >> 16) & 1u;
    u += 0x7fffu + lsb;
    return (unsigned short)(u >> 16);
}
static __device__ __forceinline__ float bf2f(unsigned short u){
    return __uint_as_float(((unsigned int)u) << 16);
}

// ---------------- sort-by-target (counting sort) ----------------
__global__ void zero_counts(int* cnt){
    cnt[threadIdx.x] = 0;
}

__global__ void hist_kernel(const int* __restrict__ tgt, int* cnt){
    int e = blockIdx.x*256 + threadIdx.x;
    if (e < EE) atomicAdd(&cnt[tgt[e]], 1);
}

__global__ void scan_kernel(const int* __restrict__ cnt, int* offs, int* cursor){
    __shared__ int s[1024];
    int tid = threadIdx.x;
    s[tid] = (tid < NN) ? cnt[tid] : 0;
    __syncthreads();
    for (int st = 1; st < 1024; st <<= 1){
        int v = (tid >= st) ? s[tid-st] : 0;
        __syncthreads();
        s[tid] += v;
        __syncthreads();
    }
    int excl = (tid == 0) ? 0 : s[tid-1];
    if (tid < NN){ offs[tid] = excl; cursor[tid] = excl; }
    if (tid == 0) offs[NN] = s[NN-1];
}

__global__ void scatter_kernel(const int* __restrict__ src, const int* __restrict__ tgt,
                               int* cursor, int* ssrc, int* epos){
    int e = blockIdx.x*256 + threadIdx.x;
    if (e < EE){
        int t = tgt[e];
        int pos = atomicAdd(&cursor[t], 1);
        ssrc[pos] = src[e];
        epos[e] = pos;
    }
}

// ---------------- edge encoder: 4 -> 16 -> 32, bf16 out, sorted order ----------------
__global__ __launch_bounds__(256) void edge_enc(
    const float* __restrict__ edge_attr,
    const float* __restrict__ w1, const float* __restrict__ b1,
    const float* __restrict__ w2, const float* __restrict__ b2,
    const int* __restrict__ epos,
    unsigned short* __restrict__ efs)
{
    __shared__ float w1s[64], b1s[16], w2s[512], b2s[32];
    int tid = threadIdx.x;
    if (tid < 64) w1s[tid] = w1[tid];
    if (tid < 16) b1s[tid] = b1[tid];
    if (tid < 32) b2s[tid] = b2[tid];
    w2s[tid] = w2[tid];
    w2s[tid+256] = w2[tid+256];
    __syncthreads();
    int e = blockIdx.x*256 + tid;
    if (e >= EE) return;
    float4 av = *(const float4*)(edge_attr + (size_t)e*4);
    float hd[16];
    #pragma unroll
    for (int i = 0; i < 16; i++){
        float v = av.x*w1s[i] + av.y*w1s[16+i] + av.z*w1s[32+i] + av.w*w1s[48+i] + b1s[i];
        hd[i] = fmaxf(v, 0.f);
    }
    unsigned short* op = efs + (size_t)epos[e]*32;
    #pragma unroll
    for (int k4 = 0; k4 < 8; k4++){
        ushort4 ub;
        float v0 = b2s[k4*4+0], v1 = b2s[k4*4+1], v2 = b2s[k4*4+2], v3 = b2s[k4*4+3];
        #pragma unroll
        for (int i = 0; i < 16; i++){
            float hv = hd[i];
            v0 += hv*w2s[i*32 + k4*4+0];
            v1 += hv*w2s[i*32 + k4*4+1];
            v2 += hv*w2s[i*32 + k4*4+2];
            v3 += hv*w2s[i*32 + k4*4+3];
        }
        ub.x = f2bf(v0); ub.y = f2bf(v1); ub.z = f2bf(v2); ub.w = f2bf(v3);
        *(ushort4*)(op + k4*4) = ub;
    }
}

// ---------------- merged conversions: tconv24 (6144) + embed-w tconv (128) + x (1024) ----------------
__global__ __launch_bounds__(256) void convert_all(
    const float* __restrict__ Wq, const float* __restrict__ Wk,
    const float* __restrict__ Wv, const float* __restrict__ Ws,
    const float* __restrict__ embed_w, const float* __restrict__ x,
    unsigned short* __restrict__ Wt, unsigned short* __restrict__ ewt,
    unsigned short* __restrict__ xb)
{
    int bid = blockIdx.x;
    int tid = threadIdx.x;
    if (bid < 6144){
        int mm = bid >> 8;
        int tile = bid & 255;
        int tk = tile >> 4, tn = tile & 15;
        int l = mm >> 2, m = mm & 3;
        const float* W = ((m==0)?Wq:(m==1)?Wk:(m==2)?Wv:Ws) + (size_t)l*512*512;
        unsigned short* dst = Wt + (size_t)mm*512*512;
        __shared__ float ts[32][33];
        int r = tid >> 3, c0 = (tid & 7)*4;
        float4 v = *(const float4*)(W + (size_t)(tk*32 + r)*512 + tn*32 + c0);
        ts[r][c0+0] = v.x; ts[r][c0+1] = v.y; ts[r][c0+2] = v.z; ts[r][c0+3] = v.w;
        __syncthreads();
        ushort4 o;
        o.x = f2bf(ts[c0+0][r]); o.y = f2bf(ts[c0+1][r]);
        o.z = f2bf(ts[c0+2][r]); o.w = f2bf(ts[c0+3][r]);
        *(ushort4*)(dst + (size_t)(tn*32 + r)*512 + tk*32 + c0) = o;
    } else if (bid < 6144 + 128){
        int tile = bid - 6144;
        int tn = tile & 15, tk = tile >> 4;   // 16 n-tiles x 8 k-tiles
        __shared__ float ts2[32][33];
        int r = tid >> 3, c0 = (tid & 7)*4;
        float4 v = *(const float4*)(embed_w + (size_t)(tk*32 + r)*512 + tn*32 + c0);
        ts2[r][c0+0] = v.x; ts2[r][c0+1] = v.y; ts2[r][c0+2] = v.z; ts2[r][c0+3] = v.w;
        __syncthreads();
        ushort4 o;
        o.x = f2bf(ts2[c0+0][r]); o.y = f2bf(ts2[c0+1][r]);
        o.z = f2bf(ts2[c0+2][r]); o.w = f2bf(ts2[c0+3][r]);
        *(ushort4*)(ewt + (size_t)(tn*32 + r)*256 + tk*32 + c0) = o;
    } else {
        int row = bid - 6144 - 128;           // 0..1023
        xb[(size_t)row*256 + tid] = (row < NN) ? f2bf(x[(size_t)row*256 + tid]) : (unsigned short)0;
    }
}

// ---------------- MFMA embed GEMM: h0 = x@W + b + pe (K=256), fp32 + bf16 out ----------------
__global__ __launch_bounds__(256) void gemm_embed_mfma(
    const unsigned short* __restrict__ xb,
    const unsigned short* __restrict__ ewt,
    const float* __restrict__ bias, const float* __restrict__ pe,
    float* __restrict__ C, unsigned short* __restrict__ hb)
{
    int bid = blockIdx.x;
    int mt = bid >> 2, nt = bid & 3;
    int row0 = mt*64, col0 = nt*128;

    __shared__ __align__(16) unsigned short As[64*40];
    __shared__ __align__(16) unsigned short Bs[128*40];

    int tid = threadIdx.x;
    int wid = tid >> 6, l = tid & 63;
    int wm = wid >> 1, wn = wid & 1;

    f32x4 acc[2][4] = {};
    int ar = tid >> 2, akq = tid & 3;
    for (int k0 = 0; k0 < 256; k0 += 32){
        *(uint4*)&As[ar*40 + akq*8]      = *(const uint4*)&xb[(size_t)(row0+ar)*256 + k0 + akq*8];
        *(uint4*)&Bs[ar*40 + akq*8]      = *(const uint4*)&ewt[(size_t)(col0+ar)*256 + k0 + akq*8];
        *(uint4*)&Bs[(ar+64)*40 + akq*8] = *(const uint4*)&ewt[(size_t)(col0+ar+64)*256 + k0 + akq*8];
        __syncthreads();
        short8v a0 = *(const short8v*)&As[(wm*32 + (l&15))*40 + (l>>4)*8];
        short8v a1 = *(const short8v*)&As[(wm*32 + 16 + (l&15))*40 + (l>>4)*8];
        #pragma unroll
        for (int nj = 0; nj < 4; nj++){
            short8v b = *(const short8v*)&Bs[(wn*64 + nj*16 + (l&15))*40 + (l>>4)*8];
            acc[0][nj] = __builtin_amdgcn_mfma_f32_16x16x32_bf16(a0, b, acc[0][nj], 0, 0, 0);
            acc[1][nj] = __builtin_amdgcn_mfma_f32_16x16x32_bf16(a1, b, acc[1][nj], 0, 0, 0);
        }
        __syncthreads();
    }
    int rbase = (l >> 4)*4, cl = l & 15;
    #pragma unroll
    for (int mi = 0; mi < 2; mi++)
        #pragma unroll
        for (int nj = 0; nj < 4; nj++)
            #pragma unroll
            for (int r = 0; r < 4; r++){
                int grow = row0 + wm*32 + mi*16 + rbase + r;
                int gcol = col0 + wn*64 + nj*16 + cl;
                if (grow < NN){
                    float v = acc[mi][nj][r] + bias[gcol] + pe[(size_t)grow*512 + gcol];
                    C[(size_t)grow*512 + gcol] = v;
                    hb[(size_t)grow*512 + gcol] = f2bf(v);
                }
            }
}

// ---------------- bf16 MFMA GEMM, 64x64 tiles, reg-prefetch ----------------
__global__ __launch_bounds__(256) void gemm_qkvs_mfma(
    const unsigned short* __restrict__ hb,
    const unsigned short* __restrict__ Wt,
    const float* __restrict__ qb, const float* __restrict__ kb,
    const float* __restrict__ vb, const float* __restrict__ sb,
    float* __restrict__ Q, unsigned short* __restrict__ K16,
    unsigned short* __restrict__ V16, float* __restrict__ S)
{
    int bid = blockIdx.x;
    int mat = bid >> 7;
    int rem = bid & 127;
    int mt = rem >> 3, nt = rem & 7;
    int row0 = mt*64, col0 = nt*64;
    const unsigned short* W = Wt + (size_t)mat*512*512;
    const float* bias = (mat==0)?qb:(mat==1)?kb:(mat==2)?vb:sb;

    __shared__ __align__(16) unsigned short As[64*72];
    __shared__ __align__(16) unsigned short Bs[64*72];

    int tid = threadIdx.x;
    int wid = tid >> 6, l = tid & 63;
    int wm = wid >> 1, wn = wid & 1;

    f32x4 acc[2][2] = {};
    int lr = tid >> 2;
    int lc = (tid & 3)*2;
    const unsigned short* ga = hb + (size_t)(row0+lr)*512 + lc*8;
    const unsigned short* gb = W  + (size_t)(col0+lr)*512 + lc*8;

    uint4 ra0 = *(const uint4*)(ga);
    uint4 ra1 = *(const uint4*)(ga + 8);
    uint4 rb0 = *(const uint4*)(gb);
    uint4 rb1 = *(const uint4*)(gb + 8);

    for (int k0 = 0; k0 < 512; k0 += 64){
        __syncthreads();
        *(uint4*)&As[lr*72 + lc*8]     = ra0;
        *(uint4*)&As[lr*72 + lc*8 + 8] = ra1;
        *(uint4*)&Bs[lr*72 + lc*8]     = rb0;
        *(uint4*)&Bs[lr*72 + lc*8 + 8] = rb1;
        __syncthreads();
        if (k0 + 64 < 512){
            ra0 = *(const uint4*)(ga + k0 + 64);
            ra1 = *(const uint4*)(ga + k0 + 72);
            rb0 = *(const uint4*)(gb + k0 + 64);
            rb1 = *(const uint4*)(gb + k0 + 72);
        }
        #pragma unroll
        for (int ks = 0; ks < 2; ks++){
            short8v a0 = *(const short8v*)&As[(wm*32 + (l&15))*72      + ks*32 + (l>>4)*8];
            short8v a1 = *(const short8v*)&As[(wm*32 + 16 + (l&15))*72 + ks*32 + (l>>4)*8];
            short8v b0 = *(const short8v*)&Bs[(wn*32 + (l&15))*72      + ks*32 + (l>>4)*8];
            short8v b1 = *(const short8v*)&Bs[(wn*32 + 16 + (l&15))*72 + ks*32 + (l>>4)*8];
            acc[0][0] = __builtin_amdgcn_mfma_f32_16x16x32_bf16(a0, b0, acc[0][0], 0, 0, 0);
            acc[0][1] = __builtin_amdgcn_mfma_f32_16x16x32_bf16(a0, b1, acc[0][1], 0, 0, 0);
            acc[1][0] = __builtin_amdgcn_mfma_f32_16x16x32_bf16(a1, b0, acc[1][0], 0, 0, 0);
            acc[1][1] = __builtin_amdgcn_mfma_f32_16x16x32_bf16(a1, b1, acc[1][1], 0, 0, 0);
        }
    }
    int rbase = (l >> 4)*4, cl = l & 15;
    #pragma unroll
    for (int mi = 0; mi < 2; mi++)
        #pragma unroll
        for (int nj = 0; nj < 2; nj++)
            #pragma unroll
            for (int r = 0; r < 4; r++){
                int grow = row0 + wm*32 + mi*16 + rbase + r;
                int gcol = col0 + wn*32 + nj*16 + cl;
                if (grow < NN){
                    float v = acc[mi][nj][r] + bias[gcol];
                    if (mat == 0)      Q[(size_t)grow*512 + gcol] = v;
                    else if (mat == 1) K16[(size_t)grow*512 + gcol] = f2bf(v);
                    else if (mat == 2) V16[(size_t)grow*512 + gcol] = f2bf(v);
                    else               S[(size_t)grow*512 + gcol] = v;
                }
            }
}

// ------------- per-node-half attention: 4 heads per block, 2000 blocks -------------
// Writes x_pre = attention output (r + oe) only; skip/residual/LN in ln_skip.
__global__ __launch_bounds__(256) void attn_h4(
    const float* __restrict__ Qm, const unsigned short* __restrict__ Km,
    const unsigned short* __restrict__ Vm,
    const unsigned short* __restrict__ efs, const float* __restrict__ e_w_l,
    const int* __restrict__ ssrc, const int* __restrict__ offs,
    float* __restrict__ x_pre)
{
    int tid = threadIdx.x;
    int b = blockIdx.x;
    int t = b >> 1;
    int hh0 = (b & 1)*4;              // head base (0 or 4)

    __shared__ float q_s[4*68];
    __shared__ float qe_s[4*36];
    __shared__ float sc_s[MAXDEG*4];
    __shared__ int   src_s[MAXDEG];
    __shared__ float pv_s[4*256];
    __shared__ float pe_s[4*128];
    __shared__ float s_s[128];
    __shared__ float red[16], red2[16];
    __shared__ float m_s[4], d_s[4];

    // q for own 4 heads (256 channels)
    q_s[(tid>>6)*68 + (tid&63)] = Qm[(size_t)t*512 + hh0*64 + tid];
    __syncthreads();
    // qe[h][d] = q[h] . e_w[d, (hh0+h)*64 ..]
    if (tid < 128){
        int h = tid >> 5, d = tid & 31;
        const float* wrow = e_w_l + (size_t)d*512 + (hh0+h)*64;
        const float* qh = q_s + h*68;
        float a = 0.f;
        #pragma unroll
        for (int c = 0; c < 64; c++) a += qh[c]*wrow[c];
        qe_s[h*36 + d] = a;
    }
    int start = offs[t], deg = offs[t+1] - start;
    __syncthreads();

    // ---- pass 1: scores. 8 crews of 32 lanes; lane: head h = l>>3, sub = l&7 ----
    int cw = tid >> 5, l = tid & 31;
    int h = l >> 3, sub = l & 7;
    const float4* qp4  = (const float4*)(q_s + h*68 + sub*8);
    float4 qa0 = qp4[0], qa1 = qp4[1];
    float4 qev = *(const float4*)(qe_s + h*36 + sub*4);
    float lmax = -1e30f;
    #pragma unroll 2
    for (int i = cw; i < deg; i += 8){
        int s = ssrc[start + i];
        if (l == 0) src_s[i] = s;
        short8v kv = *(const short8v*)(Km + (size_t)s*512 + (hh0 + h)*64 + sub*8);
        ushort4 ev = *(const ushort4*)(efs + (size_t)(start+i)*32 + sub*4);
        float p;
        p  = qa0.x*bf2f((unsigned short)kv[0]) + qa0.y*bf2f((unsigned short)kv[1])
           + qa0.z*bf2f((unsigned short)kv[2]) + qa0.w*bf2f((unsigned short)kv[3]);
        p += qa1.x*bf2f((unsigned short)kv[4]) + qa1.y*bf2f((unsigned short)kv[5])
           + qa1.z*bf2f((unsigned short)kv[6]) + qa1.w*bf2f((unsigned short)kv[7]);
        p += qev.x*bf2f(ev.x) + qev.y*bf2f(ev.y)
           + qev.z*bf2f(ev.z) + qev.w*bf2f(ev.w);
        p += __shfl_xor(p, 1);
        p += __shfl_xor(p, 2);
        p += __shfl_xor(p, 4);
        p *= SCALE;
        lmax = fmaxf(lmax, p);
        if (sub == 0) sc_s[i*4 + h] = p;
    }
    // reduce max: over crews-in-wave (xor 32), then cross-wave via LDS
    lmax = fmaxf(lmax, __shfl_xor(lmax, 32));
    {
        int wl = tid & 63;
        if (wl < 32 && (wl & 7) == 0) red[(tid>>6)*4 + (wl>>3)] = lmax;
    }
    __syncthreads();
    if (tid < 4){
        float m = fmaxf(fmaxf(red[tid], red[4+tid]), fmaxf(red[8+tid], red[12+tid]));
        m_s[tid] = m;
    }
    __syncthreads();

    // ---- exp sweep + denominator ----
    {
        int he = tid & 3, ie = tid >> 2;
        float mh = m_s[he];
        float den = 0.f;
        for (int i = ie; i < deg; i += 64){
            float al = __expf(sc_s[i*4 + he] - mh);
            sc_s[i*4 + he] = al;
            den += al;
        }
        den += __shfl_xor(den, 4);
        den += __shfl_xor(den, 8);
        den += __shfl_xor(den, 16);
        den += __shfl_xor(den, 32);
        if ((tid & 63) < 4) red2[(tid>>6)*4 + (tid & 3)] = den;
    }
    __syncthreads();
    if (tid < 4) d_s[tid] = red2[tid] + red2[4+tid] + red2[8+tid] + red2[12+tid];
    __syncthreads();

    // ---- pass 2: V + e accumulation, 4 edge-groups of 64 lanes ----
    {
        int g = tid >> 6, c4 = tid & 63;
        int h2 = c4 >> 4;
        int dp = (c4 & 15)*2;
        float4 accV = make_float4(0.f,0.f,0.f,0.f);
        float2 accE = make_float2(0.f,0.f);
        #pragma unroll 4
        for (int i = g; i < deg; i += 4){
            int s = src_s[i];
            float al = sc_s[i*4 + h2];
            ushort4 v = *(const ushort4*)(Vm + (size_t)s*512 + hh0*64 + c4*4);
            unsigned int e2 = *(const unsigned int*)(efs + (size_t)(start+i)*32 + dp);
            accV.x += al*bf2f(v.x); accV.y += al*bf2f(v.y);
            accV.z += al*bf2f(v.z); accV.w += al*bf2f(v.w);
            accE.x += al*bf2f((unsigned short)(e2 & 0xffffu));
            accE.y += al*bf2f((unsigned short)(e2 >> 16));
        }
        *(float4*)&pv_s[g*256 + c4*4] = accV;
        *(float2*)&pe_s[g*128 + c4*2] = accE;
    }
    __syncthreads();
    if (tid < 128){
        int h3 = tid >> 5, d = tid & 31;
        int c4s = h3*16 + (d >> 1), comp = d & 1;
        float dv = d_s[h3];
        float invd = (dv > 0.f) ? 1.f/dv : 0.f;
        float ssum = pe_s[c4s*2+comp] + pe_s[128 + c4s*2+comp]
                   + pe_s[256 + c4s*2+comp] + pe_s[384 + c4s*2+comp];
        s_s[h3*32 + d] = ssum * invd;
    }
    __syncthreads();

    int c = tid;
    int hh = c >> 6;
    float dv = d_s[hh];
    float invd = (dv > 0.f) ? 1.f/dv : 0.f;
    float vtot = pv_s[c] + pv_s[256+c] + pv_s[512+c] + pv_s[768+c];
    float r = vtot * invd;
    float oe = 0.f;
    const float* sp = s_s + hh*32;
    #pragma unroll
    for (int d = 0; d < 32; d++) oe += sp[d]*e_w_l[(size_t)d*512 + hh0*64 + c];
    x_pre[(size_t)t*512 + hh0*64 + c] = r + oe;
}

// ------------- skip + residual + LayerNorm -------------
__global__ __launch_bounds__(256) void ln_skip(
    const float* __restrict__ x_pre, const float* __restrict__ SKm,
    const float* __restrict__ hcur,
    const float* __restrict__ ln_g_l, const float* __restrict__ ln_b_l,
    float* __restrict__ hnext, unsigned short* __restrict__ hbn)
{
    int tid = threadIdx.x, t = blockIdx.x;
    __shared__ float red[4], red2[4];
    float x0 = x_pre[(size_t)t*512 + tid]       + SKm[(size_t)t*512 + tid]       + hcur[(size_t)t*512 + tid];
    float x1 = x_pre[(size_t)t*512 + 256 + tid] + SKm[(size_t)t*512 + 256 + tid] + hcur[(size_t)t*512 + 256 + tid];
    float sA = x0 + x1, sB = x0*x0 + x1*x1;
    #pragma unroll
    for (int m = 1; m <= 32; m <<= 1){
        sA += __shfl_xor(sA, m);
        sB += __shfl_xor(sB, m);
    }
    int wv = tid >> 6, ln = tid & 63;
    if (ln == 0){ red[wv] = sA; red2[wv] = sB; }
    __syncthreads();
    float tot  = red[0] + red[1] + red[2] + red[3];
    float tot2 = red2[0] + red2[1] + red2[2] + red2[3];
    float mu  = tot*(1.f/512.f);
    float var = tot2*(1.f/512.f) - mu*mu;
    float rstd = rsqrtf(var + 1e-5f);
    float y0 = (x0 - mu)*rstd*ln_g_l[tid]     + ln_b_l[tid];
    float y1 = (x1 - mu)*rstd*ln_g_l[256+tid] + ln_b_l[256+tid];
    hnext[(size_t)t*512 + tid]       = y0;
    hnext[(size_t)t*512 + 256 + tid] = y1;
    hbn[(size_t)t*512 + tid]       = f2bf(y0);
    hbn[(size_t)t*512 + 256 + tid] = f2bf(y1);
}

// ---------------- final head: dom + concat + MLP ----------------
__global__ __launch_bounds__(256) void final_head(
    const float* __restrict__ hin,
    const float* __restrict__ dom_w, const float* __restrict__ dom_b,
    const float* __restrict__ w1, const float* __restrict__ b1,
    const float* __restrict__ w2, const float* __restrict__ b2,
    float* __restrict__ out)
{
    int tid = threadIdx.x, t = blockIdx.x;
    __shared__ float h_s[512];
    __shared__ float dom_s[16];
    __shared__ float hid_s[256];
    __shared__ float red[256];
    h_s[tid]     = hin[(size_t)t*512 + tid];
    h_s[tid+256] = hin[(size_t)t*512 + 256 + tid];
    __syncthreads();
    if (tid < 16){
        float a = dom_b[tid];
        for (int i = 0; i < 512; i++) a += h_s[i]*dom_w[i*16 + tid];
        dom_s[tid] = a;
    }
    __syncthreads();
    float acc = b1[tid];
    for (int i = 0; i < 512; i++) acc += h_s[i]*w1[(size_t)i*256 + tid];
    #pragma unroll
    for (int i = 0; i < 16; i++) acc += dom_s[i]*w1[(size_t)(512+i)*256 + tid];
    hid_s[tid] = fmaxf(acc, 0.f);
    __syncthreads();
    int o = tid & 15, g = tid >> 4;
    float p = 0.f;
    #pragma unroll
    for (int j = 0; j < 16; j++) p += hid_s[g*16 + j]*w2[(g*16 + j)*16 + o];
    red[tid] = p;
    __syncthreads();
    if (tid < 16){
        float s2 = b2[tid];
        for (int gg = 0; gg < 16; gg++) s2 += red[gg*16 + tid];
        out[(size_t)t*16 + tid] = s2;
    }
}

// ---------------- launch ----------------
extern "C" void kernel_launch(void* const* d_in, const int* in_sizes, int n_in,
                              void* d_out, int out_size, void* d_ws, size_t ws_size,
                              hipStream_t stream)
{
    const float* x       = (const float*)d_in[0];
    const int*   eidx    = (const int*)  d_in[1];
    const float* eattr   = (const float*)d_in[2];
    const float* embed_w = (const float*)d_in[3];
    const float* embed_b = (const float*)d_in[4];
    const float* pe      = (const float*)d_in[5];
    const float* ee_w1   = (const float*)d_in[6];
    const float* ee_b1   = (const float*)d_in[7];
    const float* ee_w2   = (const float*)d_in[8];
    const float* ee_b2   = (const float*)d_in[9];
    const float* q_w     = (const float*)d_in[10];
    const float* q_b     = (const float*)d_in[11];
    const float* k_w     = (const float*)d_in[12];
    const float* k_b     = (const float*)d_in[13];
    const float* v_w     = (const float*)d_in[14];
    const float* v_b     = (const float*)d_in[15];
    const float* e_w     = (const float*)d_in[16];
    const float* skip_w  = (const float*)d_in[17];
    const float* skip_b  = (const float*)d_in[18];
    const float* ln_g    = (const float*)d_in[19];
    const float* ln_b    = (const float*)d_in[20];
    const float* dom_w   = (const float*)d_in[21];
    const float* dom_b   = (const float*)d_in[22];
    const float* cls_w1  = (const float*)d_in[23];
    const float* cls_b1  = (const float*)d_in[24];
    const float* cls_w2  = (const float*)d_in[25];
    const float* cls_b2  = (const float*)d_in[26];
    float* out = (float*)d_out;

    float* ws = (float*)d_ws;
    size_t o = 0;
    float* h0    = ws + o; o += (size_t)512*NN;
    float* h1    = ws + o; o += (size_t)512*NN;
    float* Qb    = ws + o; o += (size_t)512*NN;
    float* Sb    = ws + o; o += (size_t)512*NN;
    float* xpre  = ws + o; o += (size_t)512*NN;
    unsigned short* Kb16 = (unsigned short*)(ws + o); o += (size_t)1024*512/2;
    unsigned short* Vb16 = (unsigned short*)(ws + o); o += (size_t)1024*512/2;
    unsigned short* efs  = (unsigned short*)(ws + o); o += (size_t)EE*32/2;
    unsigned short* hb   = (unsigned short*)(ws + o); o += (size_t)1024*512/2;
    unsigned short* xb   = (unsigned short*)(ws + o); o += (size_t)1024*256/2;
    unsigned short* ewt  = (unsigned short*)(ws + o); o += (size_t)512*256/2;
    unsigned short* Wtb  = (unsigned short*)(ws + o); o += (size_t)24*512*512/2;
    int* cnt    = (int*)(ws + o); o += 1024;
    int* offs   = (int*)(ws + o); o += 1024;
    int* cursor = (int*)(ws + o); o += 1024;
    int* ssrc   = (int*)(ws + o); o += EE;
    int* epos   = (int*)(ws + o); o += EE;

    const int* srcp = eidx;
    const int* tgtp = eidx + EE;

    zero_counts<<<1, 1024, 0, stream>>>(cnt);
    hist_kernel<<<EE/256, 256, 0, stream>>>(tgtp, cnt);
    scan_kernel<<<1, 1024, 0, stream>>>(cnt, offs, cursor);
    scatter_kernel<<<EE/256, 256, 0, stream>>>(srcp, tgtp, cursor, ssrc, epos);
    edge_enc<<<EE/256, 256, 0, stream>>>(eattr, ee_w1, ee_b1, ee_w2, ee_b2, epos, efs);
    convert_all<<<6144 + 128 + 1024, 256, 0, stream>>>(q_w, k_w, v_w, skip_w, embed_w, x, Wtb, ewt, xb);
    gemm_embed_mfma<<<64, 256, 0, stream>>>(xb, ewt, embed_b, pe, h0, hb);

    float* hc = h0;
    float* hn = h1;
    for (int l = 0; l < LAYERS; l++){
        gemm_qkvs_mfma<<<512, 256, 0, stream>>>(
            hb, Wtb + (size_t)l*4*512*512,
            q_b + (size_t)l*512, k_b + (size_t)l*512,
            v_b + (size_t)l*512, skip_b + (size_t)l*512,
            Qb, Kb16, Vb16, Sb);
        attn_h4<<<2*NN, 256, 0, stream>>>(
            Qb, Kb16, Vb16, efs, e_w + (size_t)l*32*512,
            ssrc, offs, xpre);
        ln_skip<<<NN, 256, 0, stream>>>(
            xpre, Sb, hc,
            ln_g + (size_t)l*512, ln_b + (size_t)l*512,
            hn, hb);
        float* tmp = hc; hc = hn; hn = tmp;
    }
    final_head<<<NN, 256, 0, stream>>>(hc, dom_w, dom_b, cls_w1, cls_b1, cls_w2, cls_b2, out);
}